// Round 9
// baseline (485.820 us; speedup 1.0000x reference)
//
#include <hip/hip_runtime.h>

// NPG model: E=4 ensembles, B=16384, STATE=29, ACT=8, HID=512.
// R11 = R9 (368us banked: fused 280 + split prep) with ONE fused change:
//   leg layer2 (512->4) moved from h2c-staging+MFMA (16 barriers/half, 128
//   of the block's ~190 barriers) to an in-register fold:
//     - per cc, after the kt MFMA loop: preg[i][r](f32x4 over o=0..3) +=
//       relu(acc[i][ct][r]) * w2[col][0..3], w2 read raw f32 from global
//       (L1-cached; no LDS, no repack, no WL2p use)
//     - after cc loop: 4-step shfl_xor butterfly over l16 (lanes sharing a
//       quad's rows), one writer lane per (i,r) -> 4 LDS atomicAdd into
//       zeroed ldiff (4-way cg contention)
//   All indices compile-time; no pointer casts; no swizzles (those were the
//   proven poisons). bl2/sigma_t/mu_t applied at ldiff read sites. Leg L2
//   is now f32 (was bf16-staged) -> slightly MORE accurate. kt MFMA loop,
//   W1 streaming, pose path byte-identical to R9.
// Canary: WRITE_SIZE must stay ~1856 KB (preg spill would inflate it).

#define E_ 4
#define B_ 16384
#define H1S 520   // h1 row stride (bf16 elems), 16B-aligned, 2-way-bank-free
#define H2S 136   // h2 staging row stride (pose only now)
#define A0S 40    // a0 row stride

typedef float f32x4 __attribute__((ext_vector_type(4)));
typedef __bf16 bf16x8 __attribute__((ext_vector_type(8)));

__device__ __forceinline__ f32x4 mfma16(bf16x8 a, bf16x8 b, f32x4 c) {
  return __builtin_amdgcn_mfma_f32_16x16x32_bf16(a, b, c, 0, 0, 0);
}

// leg-format position mapping: output slot 13+k <- leg-block ib, component j
__device__ __forceinline__ void fmt_map(int k, int& ib, int& j) {
  if (k < 8) { ib = k >> 1; j = (k & 1) ? 2 : 0; }
  else { int k8 = k - 8; ib = k8 >> 1; j = (k8 & 1) ? 3 : 1; }
}

// ---------------- prep: pack weights into bf16 MFMA-B-fragment order --------
// Packed W (K x N): tiles (nt,kt) of 32x16; element ((nt*KT+kt)*64+lane)*8+j
// holds W[kt*32 + (lane>>4)*8 + j][nt*16 + (lane&15)]
__device__ __forceinline__ void pack_one(int idx, int per_e, int KT, int Kreal,
                                         int Nsrc, int Nval,
                                         const float* __restrict__ src,
                                         const float* __restrict__ sigma,
                                         __bf16* __restrict__ dst)
{
  int e = idx / per_e;
  int rem = idx - e * per_e;
  int g = rem >> 9;            // nt*KT + kt
  int nt = g / KT;
  int kt = g - nt * KT;
  int li = rem & 511;
  int lane = li >> 3, j = li & 7;
  int k = kt * 32 + (lane >> 4) * 8 + j;
  int n = nt * 16 + (lane & 15);
  float v = 0.f;
  if (k < Kreal && n < Nval) {
    v = src[(size_t)e * Kreal * Nsrc + (size_t)k * Nsrc + n];
    if (sigma) v *= 1.f / (sigma[k] + 1e-8f);   // fold input normalization
  }
  dst[idx] = (__bf16)v;
}

// Small matrices (W0 x2, W2 pose) + bias folds: gather path (cheap, cached).
__global__ void prep_small(const float* __restrict__ wl0, const float* __restrict__ wl2,
                           const float* __restrict__ wp0, const float* __restrict__ wp2,
                           const float* __restrict__ bl0, const float* __restrict__ bp0,
                           const float* __restrict__ mu_leg, const float* __restrict__ sigma_leg,
                           const float* __restrict__ mu_pose, const float* __restrict__ sigma_pose,
                           __bf16* __restrict__ WL0p, __bf16* __restrict__ WL2p,
                           __bf16* __restrict__ WP0p, __bf16* __restrict__ WP2p,
                           float* __restrict__ bl0f, float* __restrict__ bp0f)
{
  const int S0 = 65536, S2 = 32768;
  const int total = 2 * (S0 + S2) + 4096;
  for (int idx0 = blockIdx.x * blockDim.x + threadIdx.x; idx0 < total;
       idx0 += gridDim.x * blockDim.x) {
    int x = idx0;
    if (x < S0)              { pack_one(x, 16384, 1, 6, 512, 512, wl0, sigma_leg, WL0p); }
    else if ((x -= S0) < S2) { pack_one(x, 8192, 16, 512, 8, 8, wl2, nullptr, WL2p); }
    else if ((x -= S2) < S0) { pack_one(x, 16384, 1, 29, 512, 512, wp0, sigma_pose, WP0p); }
    else if ((x -= S0) < S2) { pack_one(x, 8192, 16, 512, 26, 16, wp2, nullptr, WP2p); }
    else {
      x -= S2;  // bias folds: b0' = b0 - sum_k mu[k]/(sigma[k]+eps) * W0[k,:]
      if (x < 2048) {
        int e = x >> 9, n = x & 511;
        float s = bl0[e * 512 + n];
        #pragma unroll
        for (int k = 0; k < 6; ++k)
          s -= mu_leg[k] / (sigma_leg[k] + 1e-8f) * wl0[(e * 6 + k) * 512 + n];
        bl0f[e * 512 + n] = s;
      } else {
        x -= 2048;
        int e = x >> 9, n = x & 511;
        float s = bp0[e * 512 + n];
        for (int k = 0; k < 29; ++k)
          s -= mu_pose[k] / (sigma_pose[k] + 1e-8f) * wp0[(e * 29 + k) * 512 + n];
        bp0f[e * 512 + n] = s;
      }
    }
  }
}

// W1 matrices (512x512): coalesced strip packer. Block = one (mat,e,nt)
// 512x16 column strip; stage f32->bf16 in LDS coalesced, emit contiguous.
__global__ __launch_bounds__(256) void prep_w1(const float* __restrict__ wl1,
                                               const float* __restrict__ wp1,
                                               __bf16* __restrict__ WL1p,
                                               __bf16* __restrict__ WP1p)
{
  __shared__ __bf16 st[512][20];
  const int b = blockIdx.x;          // 0..255: [mat(1) | e(2) | nt(5)]
  const float* src = (b & 128) ? wp1 : wl1;
  __bf16* dst = (b & 128) ? WP1p : WL1p;
  const int e = (b >> 5) & 3, nt = b & 31;
  src += (size_t)e * 262144 + nt * 16;
  dst += (size_t)e * 262144 + (size_t)nt * 8192;
  const int t = threadIdx.x;

  const int k0 = t >> 2, nq = t & 3;
  #pragma unroll
  for (int it = 0; it < 8; ++it) {
    int k = it * 64 + k0;
    f32x4 v = *(const f32x4*)(src + (size_t)k * 512 + nq * 4);
    #pragma unroll
    for (int j = 0; j < 4; ++j) st[k][nq * 4 + j] = (__bf16)v[j];
  }
  __syncthreads();
  #pragma unroll
  for (int it = 0; it < 4; ++it) {
    int lo = it * 256 + t;           // bf16x8 index 0..1023
    int kt = lo >> 6, lane = lo & 63;
    int kb = kt * 32 + (lane >> 4) * 8;
    int n = lane & 15;
    bf16x8 o;
    #pragma unroll
    for (int j = 0; j < 8; ++j) o[j] = st[kb + j][n];
    *(bf16x8*)(dst + (size_t)lo * 8) = o;
  }
}

// ---------------- fused model kernel ----------------------------------------
__global__ __launch_bounds__(512) void fused_kernel(
    const float* __restrict__ state, const float* __restrict__ act,
    const float* __restrict__ wl2,
    const float* __restrict__ bl1, const float* __restrict__ bl2,
    const float* __restrict__ bp1, const float* __restrict__ bp2,
    const float* __restrict__ mu_t_leg, const float* __restrict__ sigma_t_leg,
    const float* __restrict__ mu_t_pose, const float* __restrict__ sigma_t_pose,
    const __bf16* __restrict__ WL0p, const __bf16* __restrict__ WL1p,
    const __bf16* __restrict__ WP0p, const __bf16* __restrict__ WP1p,
    const __bf16* __restrict__ WP2p,
    const float* __restrict__ bl0f, const float* __restrict__ bp0f,
    float* __restrict__ out)
{
  __shared__ alignas(16) __bf16 h1[128 * H1S];   // 133120 B
  __shared__ alignas(16) __bf16 h2c[64 * H2S];   // 17408 B (union with a0)
  __shared__ float ldiff[64][16];                // 4096 B (raw L2 sums now)
  __shared__ float legacc[64][16];               // 4096 B  -> total 158 KB
  __bf16* a0s = h2c;                             // a0 <=128*40=10240B, fits

  const int tid = threadIdx.x;
  const int wv = tid >> 6;        // wave 0..7
  const int lane = tid & 63;
  const int quad = lane >> 4;
  const int l16 = lane & 15;
  const int b0 = blockIdx.x * 64;

  for (int i = tid; i < 64 * 16; i += 512) ((float*)legacc)[i] = 0.f;
  f32x4 posacc = {0.f, 0.f, 0.f, 0.f};
  __syncthreads();

  for (int e = 0; e < E_; ++e) {
    const float* se = state + (size_t)e * B_ * 29;
    const float* ae = act + (size_t)e * B_ * 8;
    const float* w2e = wl2 + (size_t)e * 4096;   // (512,8) f32, o=0..3 used

    // zero leg-L2 accumulators (built via cross-wave LDS atomics)
    for (int i = tid; i < 64 * 16; i += 512) ((float*)ldiff)[i] = 0.f;

    // ================= leg MLP: 2 passes of 128 leg rows =================
    for (int half = 0; half < 2; ++half) {
      __syncthreads();   // h1/a0s free (prior readers done); ldiff zero visible
      // ---- a0 build: 128 rows (ib*32+t) x 32 cols (6 real)
      for (int i = tid; i < 128 * 32; i += 512) {
        int r = i >> 5, c = i & 31;
        float v = 0.f;
        if (c < 6) {
          int ib = r >> 5;
          int b = b0 + half * 32 + (r & 31);
          const float* sp = se + (size_t)b * 29;
          if (c == 0) v = sp[13 + 2 * ib];
          else if (c == 1) v = sp[21 + 2 * ib];
          else if (c == 2) v = sp[14 + 2 * ib];
          else if (c == 3) v = sp[22 + 2 * ib];
          else if (c == 4) v = ae[(size_t)b * 8 + 2 * ib];
          else v = ae[(size_t)b * 8 + 2 * ib + 1];
        }
        a0s[r * A0S + c] = (__bf16)v;
      }
      __syncthreads();

      // ---- layer0: h1(128x512) = relu(A0 @ W0 + b0'); wave owns 4 col-tiles
      {
        const __bf16* W0 = WL0p + (size_t)e * 16384;
        const float* b0v = bl0f + e * 512;
        bf16x8 bfr[4]; float bs[4];
        #pragma unroll
        for (int i = 0; i < 4; ++i) {
          int ct = wv * 4 + i;
          bfr[i] = *(const bf16x8*)(W0 + ((size_t)ct * 64 + lane) * 8);
          bs[i] = b0v[ct * 16 + l16];
        }
        for (int rt = 0; rt < 8; ++rt) {
          bf16x8 afr = *(const bf16x8*)&a0s[(rt * 16 + l16) * A0S + quad * 8];
          #pragma unroll
          for (int i = 0; i < 4; ++i) {
            f32x4 acc = {bs[i], bs[i], bs[i], bs[i]};
            acc = mfma16(afr, bfr[i], acc);
            int col = (wv * 4 + i) * 16 + l16;
            #pragma unroll
            for (int r = 0; r < 4; ++r)
              h1[(rt * 16 + quad * 4 + r) * H1S + col] = (__bf16)fmaxf(acc[r], 0.f);
          }
        }
      }
      __syncthreads();

      // ---- layer1 (128x512x512) + register-fused layer2 (no barriers)
      const __bf16* W1 = WL1p + (size_t)e * 262144;
      const float* b1v = bl1 + e * 512;
      const int rg = wv >> 2, cg = wv & 3;
      f32x4 preg[4][4];                  // [i][r], f32x4 over outputs o=0..3
      #pragma unroll
      for (int i = 0; i < 4; ++i)
        #pragma unroll
        for (int r = 0; r < 4; ++r) preg[i][r] = (f32x4){0.f, 0.f, 0.f, 0.f};

      for (int cc = 0; cc < 4; ++cc) {
        f32x4 acc[4][2];
        #pragma unroll
        for (int ct = 0; ct < 2; ++ct) {
          float bias = b1v[cc * 128 + cg * 32 + ct * 16 + l16];
          #pragma unroll
          for (int i = 0; i < 4; ++i) acc[i][ct] = (f32x4){bias, bias, bias, bias};
        }
        const __bf16* Wc = W1 + (size_t)(cc * 8 + cg * 2) * 8192;
        #pragma unroll 4
        for (int kt = 0; kt < 16; ++kt) {
          bf16x8 afr[4];
          #pragma unroll
          for (int i = 0; i < 4; ++i)
            afr[i] = *(const bf16x8*)&h1[(rg * 64 + i * 16 + l16) * H1S + kt * 32 + quad * 8];
          #pragma unroll
          for (int ct = 0; ct < 2; ++ct) {
            bf16x8 bfr = *(const bf16x8*)(Wc + (((size_t)ct * 16 + kt) * 64 + lane) * 8);
            #pragma unroll
            for (int i = 0; i < 4; ++i) acc[i][ct] = mfma16(afr[i], bfr, acc[i][ct]);
          }
        }
        // fold L2 into preg: lane's cols are cc*128 + cg*32 + ct*16 + l16
        #pragma unroll
        for (int ct = 0; ct < 2; ++ct) {
          int col = cc * 128 + cg * 32 + ct * 16 + l16;
          f32x4 w2v = *(const f32x4*)(w2e + col * 8);   // o=0..3 (L1-cached)
          #pragma unroll
          for (int i = 0; i < 4; ++i)
            #pragma unroll
            for (int r = 0; r < 4; ++r)
              preg[i][r] += w2v * fmaxf(acc[i][ct][r], 0.f);
        }
      }
      // butterfly over l16 (16 lanes of a quad share rows), then one writer
      // lane per (i,r) atomically accumulates into ldiff (cg contention = 4)
      #pragma unroll
      for (int i = 0; i < 4; ++i)
        #pragma unroll
        for (int r = 0; r < 4; ++r) {
          f32x4 p = preg[i][r];
          #pragma unroll
          for (int c = 0; c < 4; ++c) {
            p[c] += __shfl_xor(p[c], 1);
            p[c] += __shfl_xor(p[c], 2);
            p[c] += __shfl_xor(p[c], 4);
            p[c] += __shfl_xor(p[c], 8);
          }
          if (l16 == i * 4 + r) {
            int L = rg * 64 + i * 16 + quad * 4 + r;   // leg row = ib*32 + t
            int t = half * 32 + (L & 31);
            int ib4 = (L >> 5) * 4;
            atomicAdd(&ldiff[t][ib4 + 0], p[0]);
            atomicAdd(&ldiff[t][ib4 + 1], p[1]);
            atomicAdd(&ldiff[t][ib4 + 2], p[2]);
            atomicAdd(&ldiff[t][ib4 + 3], p[3]);
          }
        }
    } // half

    // ================= pose MLP: 64 rows =================
    __syncthreads();   // ldiff atomics complete, h2c free
    for (int i = tid; i < 64 * 32; i += 512) {
      int t = i >> 5, c = i & 31;
      float v = 0.f;
      if (c < 13) v = se[(size_t)(b0 + t) * 29 + c];
      else if (c < 29) {
        int ib, j; fmt_map(c - 13, ib, j);
        v = (ldiff[t][ib * 4 + j] + bl2[e * 8 + j]) * (sigma_t_leg[j] + 1e-8f)
            + mu_t_leg[j];
      }
      a0s[t * A0S + c] = (__bf16)v;
    }
    for (int i = tid; i < 64 * 16; i += 512) {   // legs output accumulation
      int t = i >> 4, k = i & 15;
      int ib, j; fmt_map(k, ib, j);
      float d = (ldiff[t][ib * 4 + j] + bl2[e * 8 + j]) * (sigma_t_leg[j] + 1e-8f)
                + mu_t_leg[j];
      legacc[t][k] += se[(size_t)(b0 + t) * 29 + 13 + k] + d;
    }
    __syncthreads();

    // ---- pose layer0: h1(64x512)
    {
      const __bf16* W0 = WP0p + (size_t)e * 16384;
      const float* b0v = bp0f + e * 512;
      bf16x8 bfr[4]; float bs[4];
      #pragma unroll
      for (int i = 0; i < 4; ++i) {
        int ct = wv * 4 + i;
        bfr[i] = *(const bf16x8*)(W0 + ((size_t)ct * 64 + lane) * 8);
        bs[i] = b0v[ct * 16 + l16];
      }
      for (int rt = 0; rt < 4; ++rt) {
        bf16x8 afr = *(const bf16x8*)&a0s[(rt * 16 + l16) * A0S + quad * 8];
        #pragma unroll
        for (int i = 0; i < 4; ++i) {
          f32x4 acc = {bs[i], bs[i], bs[i], bs[i]};
          acc = mfma16(afr, bfr[i], acc);
          int col = (wv * 4 + i) * 16 + l16;
          #pragma unroll
          for (int r = 0; r < 4; ++r)
            h1[(rt * 16 + quad * 4 + r) * H1S + col] = (__bf16)fmaxf(acc[r], 0.f);
        }
      }
    }
    __syncthreads();

    // ---- pose layer1 (64x512x512) + fused layer2 (N=13 -> 1 col-tile)
    {
      const __bf16* W1 = WP1p + (size_t)e * 262144;
      const __bf16* W2 = WP2p + (size_t)e * 8192;
      const float* b1v = bp1 + e * 512;
      float bvp = bp2[e * 26 + l16];
      f32x4 po = {bvp, bvp, bvp, bvp};       // waves 0..3 own row-tiles 0..3

      for (int cc2 = 0; cc2 < 2; ++cc2) {
        f32x4 acc[4][2];
        #pragma unroll
        for (int ct = 0; ct < 2; ++ct) {
          float bias = b1v[cc2 * 256 + wv * 32 + ct * 16 + l16];
          #pragma unroll
          for (int i = 0; i < 4; ++i) acc[i][ct] = (f32x4){bias, bias, bias, bias};
        }
        const __bf16* Wc = W1 + (size_t)(cc2 * 16 + wv * 2) * 8192;
        #pragma unroll 4
        for (int kt = 0; kt < 16; ++kt) {
          bf16x8 afr[4];
          #pragma unroll
          for (int i = 0; i < 4; ++i)
            afr[i] = *(const bf16x8*)&h1[(i * 16 + l16) * H1S + kt * 32 + quad * 8];
          #pragma unroll
          for (int ct = 0; ct < 2; ++ct) {
            bf16x8 bfr = *(const bf16x8*)(Wc + (((size_t)ct * 16 + kt) * 64 + lane) * 8);
            #pragma unroll
            for (int i = 0; i < 4; ++i) acc[i][ct] = mfma16(afr[i], bfr, acc[i][ct]);
          }
        }
        // stage in two 128-col halves (cols cg<4 then cg>=4)
        #pragma unroll
        for (int hh = 0; hh < 2; ++hh) {
          __syncthreads();
          if ((wv >> 2) == hh) {
            int cgl = wv & 3;
            #pragma unroll
            for (int i = 0; i < 4; ++i)
              #pragma unroll
              for (int ct = 0; ct < 2; ++ct)
                #pragma unroll
                for (int r = 0; r < 4; ++r)
                  h2c[(i * 16 + quad * 4 + r) * H2S + cgl * 32 + ct * 16 + l16] =
                      (__bf16)fmaxf(acc[i][ct][r], 0.f);
          }
          __syncthreads();
          if (wv < 4) {
            #pragma unroll
            for (int k2 = 0; k2 < 4; ++k2) {
              bf16x8 afr2 = *(const bf16x8*)&h2c[(wv * 16 + l16) * H2S + k2 * 32 + quad * 8];
              bf16x8 bfr2 = *(const bf16x8*)(W2 + ((size_t)(cc2 * 8 + hh * 4 + k2) * 64 + lane) * 8);
              po = mfma16(afr2, bfr2, po);
            }
          }
        }
      }
      // pose epilogue: accumulate into registers across ensembles
      if (wv < 4 && l16 < 13) {
        float sc = sigma_t_pose[l16] + 1e-8f;
        float mv = mu_t_pose[l16];
        #pragma unroll
        for (int r = 0; r < 4; ++r) {
          int row = wv * 16 + quad * 4 + r;
          posacc[r] += po[r] * sc + mv + se[(size_t)(b0 + row) * 29 + l16];
        }
      }
    }
  } // e

  // ================= final writes: mean over ensembles =================
  if (wv < 4 && l16 < 13) {
    #pragma unroll
    for (int r = 0; r < 4; ++r) {
      int row = wv * 16 + quad * 4 + r;
      out[(size_t)(b0 + row) * 29 + l16] = 0.25f * posacc[r];
    }
  }
  for (int i = tid; i < 64 * 16; i += 512) {
    int t = i >> 4, k = i & 15;
    out[(size_t)(b0 + t) * 29 + 13 + k] = 0.25f * legacc[t][k];
  }
}

// ---------------- launch ----------------------------------------------------
extern "C" void kernel_launch(void* const* d_in, const int* in_sizes, int n_in,
                              void* d_out, int out_size, void* d_ws, size_t ws_size,
                              hipStream_t stream) {
  const float* state = (const float*)d_in[0];
  const float* act = (const float*)d_in[1];
  const float* wl0 = (const float*)d_in[2];
  const float* bl0 = (const float*)d_in[3];
  const float* wl1 = (const float*)d_in[4];
  const float* bl1 = (const float*)d_in[5];
  const float* wl2 = (const float*)d_in[6];
  const float* bl2 = (const float*)d_in[7];
  const float* wp0 = (const float*)d_in[8];
  const float* bp0 = (const float*)d_in[9];
  const float* wp1 = (const float*)d_in[10];
  const float* bp1 = (const float*)d_in[11];
  const float* wp2 = (const float*)d_in[12];
  const float* bp2 = (const float*)d_in[13];
  const float* mu_leg = (const float*)d_in[14];
  const float* sigma_leg = (const float*)d_in[15];
  const float* mu_pose = (const float*)d_in[16];
  const float* sigma_pose = (const float*)d_in[17];
  const float* mu_t_leg = (const float*)d_in[18];
  const float* sigma_t_leg = (const float*)d_in[19];
  const float* mu_t_pose = (const float*)d_in[20];
  const float* sigma_t_pose = (const float*)d_in[21];
  float* out = (float*)d_out;

  char* ws = (char*)d_ws;
  __bf16* WL0p = (__bf16*)(ws);
  __bf16* WL1p = (__bf16*)(ws + 131072);
  __bf16* WL2p = (__bf16*)(ws + 2228224);
  __bf16* WP0p = (__bf16*)(ws + 2293760);
  __bf16* WP1p = (__bf16*)(ws + 2424832);
  __bf16* WP2p = (__bf16*)(ws + 4521984);
  float* bl0f = (float*)(ws + 4587520);
  float* bp0f = (float*)(ws + 4595712);

  prep_small<<<256, 256, 0, stream>>>(wl0, wl2, wp0, wp2, bl0, bp0,
                                      mu_leg, sigma_leg, mu_pose, sigma_pose,
                                      WL0p, WL2p, WP0p, WP2p, bl0f, bp0f);
  prep_w1<<<256, 256, 0, stream>>>(wl1, wp1, WL1p, WP1p);
  fused_kernel<<<256, 512, 0, stream>>>(state, act, wl2, bl1, bl2, bp1, bp2,
                                        mu_t_leg, sigma_t_leg, mu_t_pose, sigma_t_pose,
                                        WL0p, WL1p, WP0p, WP1p, WP2p,
                                        bl0f, bp0f, out);
}

// Round 10
// 378.555 us; speedup vs baseline: 1.2834x; 1.2834x over previous
//
#include <hip/hip_runtime.h>

// NPG model: E=4 ensembles, B=16384, STATE=29, ACT=8, HID=512.
// R12 = single-variable experiment: R8's fused kernel (wide 64x64 L1 wave
// tile, proven correct @301us, conflicts halved to 1.26e7, VGPR 116 no
// spill) with the kt loops restored to unroll 4 (R8 ran unroll 2 -- a
// confounded second variable vs R9's unroll-4 narrow tile @280us).
// Mechanism: unroll 4 restores load/MFMA pipeline depth; wide tile keeps
// halved LDS A-reads + halved addr VALU. 1 block/CU is LDS-capped, so
// VGPR up to 256/wave is occupancy-free. Canary: WRITE_SIZE must stay
// 1856 KB (R11's preg spill inflated it to 31.5MB -> instant revert).
// Prep: R9's split prep (proven 4x).

#define E_ 4
#define B_ 16384
#define H1S 520   // h1 row stride (bf16 elems), 16B-aligned
#define H2S 136   // h2 staging row stride
#define A0S 40    // a0 row stride

typedef float f32x4 __attribute__((ext_vector_type(4)));
typedef __bf16 bf16x8 __attribute__((ext_vector_type(8)));

__device__ __forceinline__ f32x4 mfma16(bf16x8 a, bf16x8 b, f32x4 c) {
  return __builtin_amdgcn_mfma_f32_16x16x32_bf16(a, b, c, 0, 0, 0);
}

// leg-format position mapping: output slot 13+k <- leg-block ib, component j
__device__ __forceinline__ void fmt_map(int k, int& ib, int& j) {
  if (k < 8) { ib = k >> 1; j = (k & 1) ? 2 : 0; }
  else { int k8 = k - 8; ib = k8 >> 1; j = (k8 & 1) ? 3 : 1; }
}

// ---------------- prep: pack weights into bf16 MFMA-B-fragment order --------
// Packed W (K x N): tiles (nt,kt) of 32x16; element ((nt*KT+kt)*64+lane)*8+j
// holds W[kt*32 + (lane>>4)*8 + j][nt*16 + (lane&15)]
__device__ __forceinline__ void pack_one(int idx, int per_e, int KT, int Kreal,
                                         int Nsrc, int Nval,
                                         const float* __restrict__ src,
                                         const float* __restrict__ sigma,
                                         __bf16* __restrict__ dst)
{
  int e = idx / per_e;
  int rem = idx - e * per_e;
  int g = rem >> 9;            // nt*KT + kt
  int nt = g / KT;
  int kt = g - nt * KT;
  int li = rem & 511;
  int lane = li >> 3, j = li & 7;
  int k = kt * 32 + (lane >> 4) * 8 + j;
  int n = nt * 16 + (lane & 15);
  float v = 0.f;
  if (k < Kreal && n < Nval) {
    v = src[(size_t)e * Kreal * Nsrc + (size_t)k * Nsrc + n];
    if (sigma) v *= 1.f / (sigma[k] + 1e-8f);   // fold input normalization
  }
  dst[idx] = (__bf16)v;
}

// Small matrices (W0 x2, W2 x2) + bias folds: gather path (cheap, cached).
__global__ void prep_small(const float* __restrict__ wl0, const float* __restrict__ wl2,
                           const float* __restrict__ wp0, const float* __restrict__ wp2,
                           const float* __restrict__ bl0, const float* __restrict__ bp0,
                           const float* __restrict__ mu_leg, const float* __restrict__ sigma_leg,
                           const float* __restrict__ mu_pose, const float* __restrict__ sigma_pose,
                           __bf16* __restrict__ WL0p, __bf16* __restrict__ WL2p,
                           __bf16* __restrict__ WP0p, __bf16* __restrict__ WP2p,
                           float* __restrict__ bl0f, float* __restrict__ bp0f)
{
  const int S0 = 65536, S2 = 32768;
  const int total = 2 * (S0 + S2) + 4096;
  for (int idx0 = blockIdx.x * blockDim.x + threadIdx.x; idx0 < total;
       idx0 += gridDim.x * blockDim.x) {
    int x = idx0;
    if (x < S0)              { pack_one(x, 16384, 1, 6, 512, 512, wl0, sigma_leg, WL0p); }
    else if ((x -= S0) < S2) { pack_one(x, 8192, 16, 512, 8, 8, wl2, nullptr, WL2p); }
    else if ((x -= S2) < S0) { pack_one(x, 16384, 1, 29, 512, 512, wp0, sigma_pose, WP0p); }
    else if ((x -= S0) < S2) { pack_one(x, 8192, 16, 512, 26, 16, wp2, nullptr, WP2p); }
    else {
      x -= S2;  // bias folds: b0' = b0 - sum_k mu[k]/(sigma[k]+eps) * W0[k,:]
      if (x < 2048) {
        int e = x >> 9, n = x & 511;
        float s = bl0[e * 512 + n];
        #pragma unroll
        for (int k = 0; k < 6; ++k)
          s -= mu_leg[k] / (sigma_leg[k] + 1e-8f) * wl0[(e * 6 + k) * 512 + n];
        bl0f[e * 512 + n] = s;
      } else {
        x -= 2048;
        int e = x >> 9, n = x & 511;
        float s = bp0[e * 512 + n];
        for (int k = 0; k < 29; ++k)
          s -= mu_pose[k] / (sigma_pose[k] + 1e-8f) * wp0[(e * 29 + k) * 512 + n];
        bp0f[e * 512 + n] = s;
      }
    }
  }
}

// W1 matrices (512x512): coalesced strip packer. Block = one (mat,e,nt)
// 512x16 column strip; stage f32->bf16 in LDS coalesced, emit contiguous.
__global__ __launch_bounds__(256) void prep_w1(const float* __restrict__ wl1,
                                               const float* __restrict__ wp1,
                                               __bf16* __restrict__ WL1p,
                                               __bf16* __restrict__ WP1p)
{
  __shared__ __bf16 st[512][20];
  const int b = blockIdx.x;          // 0..255: [mat(1) | e(2) | nt(5)]
  const float* src = (b & 128) ? wp1 : wl1;
  __bf16* dst = (b & 128) ? WP1p : WL1p;
  const int e = (b >> 5) & 3, nt = b & 31;
  src += (size_t)e * 262144 + nt * 16;
  dst += (size_t)e * 262144 + (size_t)nt * 8192;
  const int t = threadIdx.x;

  const int k0 = t >> 2, nq = t & 3;
  #pragma unroll
  for (int it = 0; it < 8; ++it) {
    int k = it * 64 + k0;
    f32x4 v = *(const f32x4*)(src + (size_t)k * 512 + nq * 4);
    #pragma unroll
    for (int j = 0; j < 4; ++j) st[k][nq * 4 + j] = (__bf16)v[j];
  }
  __syncthreads();
  #pragma unroll
  for (int it = 0; it < 4; ++it) {
    int lo = it * 256 + t;           // bf16x8 index 0..1023
    int kt = lo >> 6, lane = lo & 63;
    int kb = kt * 32 + (lane >> 4) * 8;
    int n = lane & 15;
    bf16x8 o;
    #pragma unroll
    for (int j = 0; j < 8; ++j) o[j] = st[kb + j][n];
    *(bf16x8*)(dst + (size_t)lo * 8) = o;
  }
}

// ---------------- fused model kernel ----------------------------------------
__global__ __launch_bounds__(512) void fused_kernel(
    const float* __restrict__ state, const float* __restrict__ act,
    const float* __restrict__ bl1, const float* __restrict__ bl2,
    const float* __restrict__ bp1, const float* __restrict__ bp2,
    const float* __restrict__ mu_t_leg, const float* __restrict__ sigma_t_leg,
    const float* __restrict__ mu_t_pose, const float* __restrict__ sigma_t_pose,
    const __bf16* __restrict__ WL0p, const __bf16* __restrict__ WL1p,
    const __bf16* __restrict__ WL2p, const __bf16* __restrict__ WP0p,
    const __bf16* __restrict__ WP1p, const __bf16* __restrict__ WP2p,
    const float* __restrict__ bl0f, const float* __restrict__ bp0f,
    float* __restrict__ out)
{
  __shared__ alignas(16) __bf16 h1[128 * H1S];   // 133120 B
  __shared__ alignas(16) __bf16 h2c[64 * H2S];   // 17408 B (union with a0)
  __shared__ float ldiff[64][16];                // 4096 B
  __shared__ float legacc[64][16];               // 4096 B  -> total 158 KB
  __bf16* a0s = h2c;                             // a0 <=128*40=5120 elems, fits

  const int tid = threadIdx.x;
  const int wv = tid >> 6;        // wave 0..7
  const int lane = tid & 63;
  const int quad = lane >> 4;
  const int l16 = lane & 15;
  const int b0 = blockIdx.x * 64;

  for (int i = tid; i < 64 * 16; i += 512) ((float*)legacc)[i] = 0.f;
  f32x4 posacc = {0.f, 0.f, 0.f, 0.f};
  __syncthreads();

  for (int e = 0; e < E_; ++e) {
    const float* se = state + (size_t)e * B_ * 29;
    const float* ae = act + (size_t)e * B_ * 8;

    // ================= leg MLP: 2 passes of 128 leg rows =================
    for (int half = 0; half < 2; ++half) {
      __syncthreads();   // h2c/a0 region free (prior readers done)
      // ---- a0 build: 128 rows (ib*32+t) x 32 cols (6 real)
      for (int i = tid; i < 128 * 32; i += 512) {
        int r = i >> 5, c = i & 31;
        float v = 0.f;
        if (c < 6) {
          int ib = r >> 5;
          int b = b0 + half * 32 + (r & 31);
          const float* sp = se + (size_t)b * 29;
          if (c == 0) v = sp[13 + 2 * ib];
          else if (c == 1) v = sp[21 + 2 * ib];
          else if (c == 2) v = sp[14 + 2 * ib];
          else if (c == 3) v = sp[22 + 2 * ib];
          else if (c == 4) v = ae[(size_t)b * 8 + 2 * ib];
          else v = ae[(size_t)b * 8 + 2 * ib + 1];
        }
        a0s[r * A0S + c] = (__bf16)v;
      }
      __syncthreads();

      // ---- layer0: h1(128x512) = relu(A0 @ W0 + b0'); wave owns 4 col-tiles
      {
        const __bf16* W0 = WL0p + (size_t)e * 16384;
        const float* b0v = bl0f + e * 512;
        bf16x8 bfr[4]; float bs[4];
        #pragma unroll
        for (int i = 0; i < 4; ++i) {
          int ct = wv * 4 + i;
          bfr[i] = *(const bf16x8*)(W0 + ((size_t)ct * 64 + lane) * 8);
          bs[i] = b0v[ct * 16 + l16];
        }
        for (int rt = 0; rt < 8; ++rt) {
          bf16x8 afr = *(const bf16x8*)&a0s[(rt * 16 + l16) * A0S + quad * 8];
          #pragma unroll
          for (int i = 0; i < 4; ++i) {
            f32x4 acc = {bs[i], bs[i], bs[i], bs[i]};
            acc = mfma16(afr, bfr[i], acc);
            int col = (wv * 4 + i) * 16 + l16;
            #pragma unroll
            for (int r = 0; r < 4; ++r)
              h1[(rt * 16 + quad * 4 + r) * H1S + col] = (__bf16)fmaxf(acc[r], 0.f);
          }
        }
      }
      __syncthreads();

      // ---- layer1 (128x512x512) + fused layer2; wave tile 64r x 64c
      const __bf16* W1 = WL1p + (size_t)e * 262144;
      const __bf16* W2 = WL2p + (size_t)e * 8192;
      const float* b1v = bl1 + e * 512;
      const int rg = wv >> 2, cg = wv & 3;
      float bv2 = (l16 < 8) ? bl2[e * 8 + l16] : 0.f;
      f32x4 oacc = {bv2, bv2, bv2, bv2};     // wave wv owns row-tile wv (l2)

      for (int cc = 0; cc < 2; ++cc) {
        f32x4 acc[4][4];
        #pragma unroll
        for (int ct = 0; ct < 4; ++ct) {
          float bias = b1v[cc * 256 + cg * 64 + ct * 16 + l16];
          #pragma unroll
          for (int i = 0; i < 4; ++i) acc[i][ct] = (f32x4){bias, bias, bias, bias};
        }
        const __bf16* Wc = W1 + (size_t)(cc * 16 + cg * 4) * 8192;
        #pragma unroll 4
        for (int kt = 0; kt < 16; ++kt) {
          bf16x8 afr[4];
          #pragma unroll
          for (int i = 0; i < 4; ++i)
            afr[i] = *(const bf16x8*)&h1[(rg * 64 + i * 16 + l16) * H1S + kt * 32 + quad * 8];
          #pragma unroll
          for (int ct = 0; ct < 4; ++ct) {
            bf16x8 bfr = *(const bf16x8*)(Wc + (((size_t)ct * 16 + kt) * 64 + lane) * 8);
            #pragma unroll
            for (int i = 0; i < 4; ++i) acc[i][ct] = mfma16(afr[i], bfr, acc[i][ct]);
          }
        }
        // stage h2: 2 sub-chunks (sc = ct-pairs) x two 64-row halves
        #pragma unroll
        for (int sc = 0; sc < 2; ++sc) {
          #pragma unroll
          for (int hh = 0; hh < 2; ++hh) {
            __syncthreads();
            if (rg == hh) {
              #pragma unroll
              for (int i = 0; i < 4; ++i)
                #pragma unroll
                for (int c2 = 0; c2 < 2; ++c2)
                  #pragma unroll
                  for (int r = 0; r < 4; ++r)
                    h2c[(i * 16 + quad * 4 + r) * H2S + cg * 32 + c2 * 16 + l16] =
                        (__bf16)fmaxf(acc[i][sc * 2 + c2][r], 0.f);
            }
            __syncthreads();
            if ((wv >> 2) == hh) {
              // staged col k2*32+x  <->  k = cc*256 + k2*64 + sc*32 + x
              #pragma unroll
              for (int k2 = 0; k2 < 4; ++k2) {
                bf16x8 afr2 = *(const bf16x8*)&h2c[((wv & 3) * 16 + l16) * H2S + k2 * 32 + quad * 8];
                bf16x8 bfr2 = *(const bf16x8*)(W2 + ((size_t)((cc * 8 + k2 * 2 + sc) * 64 + lane)) * 8);
                oacc = mfma16(afr2, bfr2, oacc);
              }
            }
          }
        }
      }
      // ---- leg epilogue: ldiff (only first 4 outputs used)
      if (l16 < 4) {
        float sc = sigma_t_leg[l16] + 1e-8f;
        float mv = mu_t_leg[l16];
        #pragma unroll
        for (int r = 0; r < 4; ++r) {
          int L = wv * 16 + quad * 4 + r;    // leg row = ib*32 + t
          ldiff[half * 32 + (L & 31)][(L >> 5) * 4 + l16] = oacc[r] * sc + mv;
        }
      }
    } // half

    // ================= pose MLP: 64 rows =================
    __syncthreads();   // ldiff ready, h2c free
    for (int i = tid; i < 64 * 32; i += 512) {
      int t = i >> 5, c = i & 31;
      float v = 0.f;
      if (c < 13) v = se[(size_t)(b0 + t) * 29 + c];
      else if (c < 29) { int ib, j; fmt_map(c - 13, ib, j); v = ldiff[t][ib * 4 + j]; }
      a0s[t * A0S + c] = (__bf16)v;
    }
    for (int i = tid; i < 64 * 16; i += 512) {   // legs output accumulation
      int t = i >> 4, k = i & 15;
      int ib, j; fmt_map(k, ib, j);
      legacc[t][k] += se[(size_t)(b0 + t) * 29 + 13 + k] + ldiff[t][ib * 4 + j];
    }
    __syncthreads();

    // ---- pose layer0: h1(64x512)
    {
      const __bf16* W0 = WP0p + (size_t)e * 16384;
      const float* b0v = bp0f + e * 512;
      bf16x8 bfr[4]; float bs[4];
      #pragma unroll
      for (int i = 0; i < 4; ++i) {
        int ct = wv * 4 + i;
        bfr[i] = *(const bf16x8*)(W0 + ((size_t)ct * 64 + lane) * 8);
        bs[i] = b0v[ct * 16 + l16];
      }
      for (int rt = 0; rt < 4; ++rt) {
        bf16x8 afr = *(const bf16x8*)&a0s[(rt * 16 + l16) * A0S + quad * 8];
        #pragma unroll
        for (int i = 0; i < 4; ++i) {
          f32x4 acc = {bs[i], bs[i], bs[i], bs[i]};
          acc = mfma16(afr, bfr[i], acc);
          int col = (wv * 4 + i) * 16 + l16;
          #pragma unroll
          for (int r = 0; r < 4; ++r)
            h1[(rt * 16 + quad * 4 + r) * H1S + col] = (__bf16)fmaxf(acc[r], 0.f);
        }
      }
    }
    __syncthreads();

    // ---- pose layer1 (64x512x512): wave owns 64-col strip; fused layer2
    {
      const __bf16* W1 = WP1p + (size_t)e * 262144;
      const __bf16* W2 = WP2p + (size_t)e * 8192;
      const float* b1v = bp1 + e * 512;
      float bvp = bp2[e * 26 + l16];
      f32x4 po = {bvp, bvp, bvp, bvp};       // waves 0..3 own row-tiles 0..3

      f32x4 acc[4][4];
      #pragma unroll
      for (int ct = 0; ct < 4; ++ct) {
        float bias = b1v[wv * 64 + ct * 16 + l16];
        #pragma unroll
        for (int i = 0; i < 4; ++i) acc[i][ct] = (f32x4){bias, bias, bias, bias};
      }
      const __bf16* Wc = W1 + (size_t)(wv * 4) * 8192;
      #pragma unroll 4
      for (int kt = 0; kt < 16; ++kt) {
        bf16x8 afr[4];
        #pragma unroll
        for (int i = 0; i < 4; ++i)
          afr[i] = *(const bf16x8*)&h1[(i * 16 + l16) * H1S + kt * 32 + quad * 8];
        #pragma unroll
        for (int ct = 0; ct < 4; ++ct) {
          bf16x8 bfr = *(const bf16x8*)(Wc + (((size_t)ct * 16 + kt) * 64 + lane) * 8);
          #pragma unroll
          for (int i = 0; i < 4; ++i) acc[i][ct] = mfma16(afr[i], bfr, acc[i][ct]);
        }
      }
      // stage Y2 in 4 rounds of 128 cols; waves {2sr,2sr+1} write, 0..3 MFMA
      #pragma unroll
      for (int sr = 0; sr < 4; ++sr) {
        __syncthreads();
        if ((wv >> 1) == sr) {
          #pragma unroll
          for (int i = 0; i < 4; ++i)
            #pragma unroll
            for (int ct = 0; ct < 4; ++ct)
              #pragma unroll
              for (int r = 0; r < 4; ++r)
                h2c[(i * 16 + quad * 4 + r) * H2S + (wv & 1) * 64 + ct * 16 + l16] =
                    (__bf16)fmaxf(acc[i][ct][r], 0.f);
        }
        __syncthreads();
        if (wv < 4) {
          // staged col k2*32+x  <->  k = sr*128 + k2*32 + x
          #pragma unroll
          for (int k2 = 0; k2 < 4; ++k2) {
            bf16x8 afr2 = *(const bf16x8*)&h2c[(wv * 16 + l16) * H2S + k2 * 32 + quad * 8];
            bf16x8 bfr2 = *(const bf16x8*)(W2 + ((size_t)((sr * 4 + k2) * 64 + lane)) * 8);
            po = mfma16(afr2, bfr2, po);
          }
        }
      }
      // pose epilogue: accumulate into registers across ensembles
      if (wv < 4 && l16 < 13) {
        float sc = sigma_t_pose[l16] + 1e-8f;
        float mv = mu_t_pose[l16];
        #pragma unroll
        for (int r = 0; r < 4; ++r) {
          int row = wv * 16 + quad * 4 + r;
          posacc[r] += po[r] * sc + mv + se[(size_t)(b0 + row) * 29 + l16];
        }
      }
    }
  } // e

  // ================= final writes: mean over ensembles =================
  if (wv < 4 && l16 < 13) {
    #pragma unroll
    for (int r = 0; r < 4; ++r) {
      int row = wv * 16 + quad * 4 + r;
      out[(size_t)(b0 + row) * 29 + l16] = 0.25f * posacc[r];
    }
  }
  for (int i = tid; i < 64 * 16; i += 512) {
    int t = i >> 4, k = i & 15;
    out[(size_t)(b0 + t) * 29 + 13 + k] = 0.25f * legacc[t][k];
  }
}

// ---------------- launch ----------------------------------------------------
extern "C" void kernel_launch(void* const* d_in, const int* in_sizes, int n_in,
                              void* d_out, int out_size, void* d_ws, size_t ws_size,
                              hipStream_t stream) {
  const float* state = (const float*)d_in[0];
  const float* act = (const float*)d_in[1];
  const float* wl0 = (const float*)d_in[2];
  const float* bl0 = (const float*)d_in[3];
  const float* wl1 = (const float*)d_in[4];
  const float* bl1 = (const float*)d_in[5];
  const float* wl2 = (const float*)d_in[6];
  const float* bl2 = (const float*)d_in[7];
  const float* wp0 = (const float*)d_in[8];
  const float* bp0 = (const float*)d_in[9];
  const float* wp1 = (const float*)d_in[10];
  const float* bp1 = (const float*)d_in[11];
  const float* wp2 = (const float*)d_in[12];
  const float* bp2 = (const float*)d_in[13];
  const float* mu_leg = (const float*)d_in[14];
  const float* sigma_leg = (const float*)d_in[15];
  const float* mu_pose = (const float*)d_in[16];
  const float* sigma_pose = (const float*)d_in[17];
  const float* mu_t_leg = (const float*)d_in[18];
  const float* sigma_t_leg = (const float*)d_in[19];
  const float* mu_t_pose = (const float*)d_in[20];
  const float* sigma_t_pose = (const float*)d_in[21];
  float* out = (float*)d_out;

  char* ws = (char*)d_ws;
  __bf16* WL0p = (__bf16*)(ws);
  __bf16* WL1p = (__bf16*)(ws + 131072);
  __bf16* WL2p = (__bf16*)(ws + 2228224);
  __bf16* WP0p = (__bf16*)(ws + 2293760);
  __bf16* WP1p = (__bf16*)(ws + 2424832);
  __bf16* WP2p = (__bf16*)(ws + 4521984);
  float* bl0f = (float*)(ws + 4587520);
  float* bp0f = (float*)(ws + 4595712);

  prep_small<<<256, 256, 0, stream>>>(wl0, wl2, wp0, wp2, bl0, bp0,
                                      mu_leg, sigma_leg, mu_pose, sigma_pose,
                                      WL0p, WL2p, WP0p, WP2p, bl0f, bp0f);
  prep_w1<<<256, 256, 0, stream>>>(wl1, wp1, WL1p, WP1p);
  fused_kernel<<<256, 512, 0, stream>>>(state, act, bl1, bl2, bp1, bp2,
                                        mu_t_leg, sigma_t_leg, mu_t_pose, sigma_t_pose,
                                        WL0p, WL1p, WL2p, WP0p, WP1p, WP2p,
                                        bl0f, bp0f, out);
}

// Round 11
// 377.709 us; speedup vs baseline: 1.2862x; 1.0022x over previous
//
#include <hip/hip_runtime.h>

// NPG model: E=4 ensembles, B=16384, STATE=29, ACT=8, HID=512.
// R13 = R9 VERBATIM (368us banked: fused 280 narrow-tile unroll-4 + split
// prep) with ONE variable changed: kt-loop unroll 4 -> 8 on the two L1 MFMA
// loops (leg + pose). Mechanism: at 1 block/CU the kernel runs 2 waves/SIMD;
// each kt step's MFMAs depend on 2 bfr loads from L2 (~200-400cy) + 4 afr
// LDS reads (~120cy). Unroll 8 doubles the load-issue window to cover that
// latency. Ledger: narrow+u4=280, wide+u2=301, wide+u4=288 -> LDS read BW
// is NOT the critical path; latency depth is the remaining candidate.
// Canary: WRITE_SIZE must stay 1856 KB (spill -> revert to R9).

#define E_ 4
#define B_ 16384
#define H1S 520   // h1 row stride (bf16 elems), 16B-aligned, 2-way-bank-free
#define H2S 136   // h2 staging row stride
#define A0S 40    // a0 row stride

typedef float f32x4 __attribute__((ext_vector_type(4)));
typedef __bf16 bf16x8 __attribute__((ext_vector_type(8)));

__device__ __forceinline__ f32x4 mfma16(bf16x8 a, bf16x8 b, f32x4 c) {
  return __builtin_amdgcn_mfma_f32_16x16x32_bf16(a, b, c, 0, 0, 0);
}

// leg-format position mapping: output slot 13+k <- leg-block ib, component j
__device__ __forceinline__ void fmt_map(int k, int& ib, int& j) {
  if (k < 8) { ib = k >> 1; j = (k & 1) ? 2 : 0; }
  else { int k8 = k - 8; ib = k8 >> 1; j = (k8 & 1) ? 3 : 1; }
}

// ---------------- prep: pack weights into bf16 MFMA-B-fragment order --------
// Packed W (K x N): tiles (nt,kt) of 32x16; element ((nt*KT+kt)*64+lane)*8+j
// holds W[kt*32 + (lane>>4)*8 + j][nt*16 + (lane&15)]
__device__ __forceinline__ void pack_one(int idx, int per_e, int KT, int Kreal,
                                         int Nsrc, int Nval,
                                         const float* __restrict__ src,
                                         const float* __restrict__ sigma,
                                         __bf16* __restrict__ dst)
{
  int e = idx / per_e;
  int rem = idx - e * per_e;
  int g = rem >> 9;            // nt*KT + kt
  int nt = g / KT;
  int kt = g - nt * KT;
  int li = rem & 511;
  int lane = li >> 3, j = li & 7;
  int k = kt * 32 + (lane >> 4) * 8 + j;
  int n = nt * 16 + (lane & 15);
  float v = 0.f;
  if (k < Kreal && n < Nval) {
    v = src[(size_t)e * Kreal * Nsrc + (size_t)k * Nsrc + n];
    if (sigma) v *= 1.f / (sigma[k] + 1e-8f);   // fold input normalization
  }
  dst[idx] = (__bf16)v;
}

// Small matrices (W0 x2, W2 x2) + bias folds: gather path (cheap, cached).
__global__ void prep_small(const float* __restrict__ wl0, const float* __restrict__ wl2,
                           const float* __restrict__ wp0, const float* __restrict__ wp2,
                           const float* __restrict__ bl0, const float* __restrict__ bp0,
                           const float* __restrict__ mu_leg, const float* __restrict__ sigma_leg,
                           const float* __restrict__ mu_pose, const float* __restrict__ sigma_pose,
                           __bf16* __restrict__ WL0p, __bf16* __restrict__ WL2p,
                           __bf16* __restrict__ WP0p, __bf16* __restrict__ WP2p,
                           float* __restrict__ bl0f, float* __restrict__ bp0f)
{
  const int S0 = 65536, S2 = 32768;
  const int total = 2 * (S0 + S2) + 4096;
  for (int idx0 = blockIdx.x * blockDim.x + threadIdx.x; idx0 < total;
       idx0 += gridDim.x * blockDim.x) {
    int x = idx0;
    if (x < S0)              { pack_one(x, 16384, 1, 6, 512, 512, wl0, sigma_leg, WL0p); }
    else if ((x -= S0) < S2) { pack_one(x, 8192, 16, 512, 8, 8, wl2, nullptr, WL2p); }
    else if ((x -= S2) < S0) { pack_one(x, 16384, 1, 29, 512, 512, wp0, sigma_pose, WP0p); }
    else if ((x -= S0) < S2) { pack_one(x, 8192, 16, 512, 26, 16, wp2, nullptr, WP2p); }
    else {
      x -= S2;  // bias folds: b0' = b0 - sum_k mu[k]/(sigma[k]+eps) * W0[k,:]
      if (x < 2048) {
        int e = x >> 9, n = x & 511;
        float s = bl0[e * 512 + n];
        #pragma unroll
        for (int k = 0; k < 6; ++k)
          s -= mu_leg[k] / (sigma_leg[k] + 1e-8f) * wl0[(e * 6 + k) * 512 + n];
        bl0f[e * 512 + n] = s;
      } else {
        x -= 2048;
        int e = x >> 9, n = x & 511;
        float s = bp0[e * 512 + n];
        for (int k = 0; k < 29; ++k)
          s -= mu_pose[k] / (sigma_pose[k] + 1e-8f) * wp0[(e * 29 + k) * 512 + n];
        bp0f[e * 512 + n] = s;
      }
    }
  }
}

// W1 matrices (512x512): coalesced strip packer. Block = one (mat,e,nt)
// 512x16 column strip; stage f32->bf16 in LDS coalesced, emit contiguous.
__global__ __launch_bounds__(256) void prep_w1(const float* __restrict__ wl1,
                                               const float* __restrict__ wp1,
                                               __bf16* __restrict__ WL1p,
                                               __bf16* __restrict__ WP1p)
{
  __shared__ __bf16 st[512][20];
  const int b = blockIdx.x;          // 0..255: [mat(1) | e(2) | nt(5)]
  const float* src = (b & 128) ? wp1 : wl1;
  __bf16* dst = (b & 128) ? WP1p : WL1p;
  const int e = (b >> 5) & 3, nt = b & 31;
  src += (size_t)e * 262144 + nt * 16;
  dst += (size_t)e * 262144 + (size_t)nt * 8192;
  const int t = threadIdx.x;

  const int k0 = t >> 2, nq = t & 3;
  #pragma unroll
  for (int it = 0; it < 8; ++it) {
    int k = it * 64 + k0;
    f32x4 v = *(const f32x4*)(src + (size_t)k * 512 + nq * 4);
    #pragma unroll
    for (int j = 0; j < 4; ++j) st[k][nq * 4 + j] = (__bf16)v[j];
  }
  __syncthreads();
  #pragma unroll
  for (int it = 0; it < 4; ++it) {
    int lo = it * 256 + t;           // bf16x8 index 0..1023
    int kt = lo >> 6, lane = lo & 63;
    int kb = kt * 32 + (lane >> 4) * 8;
    int n = lane & 15;
    bf16x8 o;
    #pragma unroll
    for (int j = 0; j < 8; ++j) o[j] = st[kb + j][n];
    *(bf16x8*)(dst + (size_t)lo * 8) = o;
  }
}

// ---------------- fused model kernel (R9 + unroll 8 on L1 kt loops) ---------
__global__ __launch_bounds__(512) void fused_kernel(
    const float* __restrict__ state, const float* __restrict__ act,
    const float* __restrict__ bl1, const float* __restrict__ bl2,
    const float* __restrict__ bp1, const float* __restrict__ bp2,
    const float* __restrict__ mu_t_leg, const float* __restrict__ sigma_t_leg,
    const float* __restrict__ mu_t_pose, const float* __restrict__ sigma_t_pose,
    const __bf16* __restrict__ WL0p, const __bf16* __restrict__ WL1p,
    const __bf16* __restrict__ WL2p, const __bf16* __restrict__ WP0p,
    const __bf16* __restrict__ WP1p, const __bf16* __restrict__ WP2p,
    const float* __restrict__ bl0f, const float* __restrict__ bp0f,
    float* __restrict__ out)
{
  __shared__ alignas(16) __bf16 h1[128 * H1S];   // 133120 B
  __shared__ alignas(16) __bf16 h2c[64 * H2S];   // 17408 B (union with a0)
  __shared__ float ldiff[64][16];                // 4096 B
  __shared__ float legacc[64][16];               // 4096 B  -> total 158 KB
  __bf16* a0s = h2c;                             // a0 <=128*40=10240B, fits

  const int tid = threadIdx.x;
  const int wv = tid >> 6;        // wave 0..7
  const int lane = tid & 63;
  const int quad = lane >> 4;
  const int l16 = lane & 15;
  const int b0 = blockIdx.x * 64;

  for (int i = tid; i < 64 * 16; i += 512) ((float*)legacc)[i] = 0.f;
  f32x4 posacc = {0.f, 0.f, 0.f, 0.f};
  __syncthreads();

  for (int e = 0; e < E_; ++e) {
    const float* se = state + (size_t)e * B_ * 29;
    const float* ae = act + (size_t)e * B_ * 8;

    // ================= leg MLP: 2 passes of 128 leg rows =================
    for (int half = 0; half < 2; ++half) {
      __syncthreads();   // h2c/a0 region free (prior readers done)
      // ---- a0 build: 128 rows (ib*32+t) x 32 cols (6 real)
      for (int i = tid; i < 128 * 32; i += 512) {
        int r = i >> 5, c = i & 31;
        float v = 0.f;
        if (c < 6) {
          int ib = r >> 5;
          int b = b0 + half * 32 + (r & 31);
          const float* sp = se + (size_t)b * 29;
          if (c == 0) v = sp[13 + 2 * ib];
          else if (c == 1) v = sp[21 + 2 * ib];
          else if (c == 2) v = sp[14 + 2 * ib];
          else if (c == 3) v = sp[22 + 2 * ib];
          else if (c == 4) v = ae[(size_t)b * 8 + 2 * ib];
          else v = ae[(size_t)b * 8 + 2 * ib + 1];
        }
        a0s[r * A0S + c] = (__bf16)v;
      }
      __syncthreads();

      // ---- layer0: h1(128x512) = relu(A0 @ W0 + b0'); wave owns 4 col-tiles
      {
        const __bf16* W0 = WL0p + (size_t)e * 16384;
        const float* b0v = bl0f + e * 512;
        bf16x8 bfr[4]; float bs[4];
        #pragma unroll
        for (int i = 0; i < 4; ++i) {
          int ct = wv * 4 + i;
          bfr[i] = *(const bf16x8*)(W0 + ((size_t)ct * 64 + lane) * 8);
          bs[i] = b0v[ct * 16 + l16];
        }
        for (int rt = 0; rt < 8; ++rt) {
          bf16x8 afr = *(const bf16x8*)&a0s[(rt * 16 + l16) * A0S + quad * 8];
          #pragma unroll
          for (int i = 0; i < 4; ++i) {
            f32x4 acc = {bs[i], bs[i], bs[i], bs[i]};
            acc = mfma16(afr, bfr[i], acc);
            int col = (wv * 4 + i) * 16 + l16;
            #pragma unroll
            for (int r = 0; r < 4; ++r)
              h1[(rt * 16 + quad * 4 + r) * H1S + col] = (__bf16)fmaxf(acc[r], 0.f);
          }
        }
      }
      __syncthreads();

      // ---- layer1 (128x512x512) + fused layer2; wave tile 64r x 32c
      const __bf16* W1 = WL1p + (size_t)e * 262144;
      const __bf16* W2 = WL2p + (size_t)e * 8192;
      const float* b1v = bl1 + e * 512;
      const int rg = wv >> 2, cg = wv & 3;
      float bv2 = (l16 < 8) ? bl2[e * 8 + l16] : 0.f;
      f32x4 oacc = {bv2, bv2, bv2, bv2};     // wave wv owns row-tile wv (l2)

      for (int cc = 0; cc < 4; ++cc) {
        f32x4 acc[4][2];
        #pragma unroll
        for (int ct = 0; ct < 2; ++ct) {
          float bias = b1v[cc * 128 + cg * 32 + ct * 16 + l16];
          #pragma unroll
          for (int i = 0; i < 4; ++i) acc[i][ct] = (f32x4){bias, bias, bias, bias};
        }
        const __bf16* Wc = W1 + (size_t)(cc * 8 + cg * 2) * 8192;
        #pragma unroll 8
        for (int kt = 0; kt < 16; ++kt) {
          bf16x8 afr[4];
          #pragma unroll
          for (int i = 0; i < 4; ++i)
            afr[i] = *(const bf16x8*)&h1[(rg * 64 + i * 16 + l16) * H1S + kt * 32 + quad * 8];
          #pragma unroll
          for (int ct = 0; ct < 2; ++ct) {
            bf16x8 bfr = *(const bf16x8*)(Wc + (((size_t)ct * 16 + kt) * 64 + lane) * 8);
            #pragma unroll
            for (int i = 0; i < 4; ++i) acc[i][ct] = mfma16(afr[i], bfr, acc[i][ct]);
          }
        }
        // stage h2 in two 64-row halves; owners accumulate layer2
        #pragma unroll
        for (int hh = 0; hh < 2; ++hh) {
          __syncthreads();
          if (rg == hh) {
            #pragma unroll
            for (int i = 0; i < 4; ++i)
              #pragma unroll
              for (int ct = 0; ct < 2; ++ct)
                #pragma unroll
                for (int r = 0; r < 4; ++r)
                  h2c[(i * 16 + quad * 4 + r) * H2S + cg * 32 + ct * 16 + l16] =
                      (__bf16)fmaxf(acc[i][ct][r], 0.f);
          }
          __syncthreads();
          if ((wv >> 2) == hh) {
            #pragma unroll
            for (int k2 = 0; k2 < 4; ++k2) {
              bf16x8 afr2 = *(const bf16x8*)&h2c[((wv & 3) * 16 + l16) * H2S + k2 * 32 + quad * 8];
              bf16x8 bfr2 = *(const bf16x8*)(W2 + ((size_t)(cc * 4 + k2) * 64 + lane) * 8);
              oacc = mfma16(afr2, bfr2, oacc);
            }
          }
        }
      }
      // ---- leg epilogue: ldiff (only first 4 outputs used)
      if (l16 < 4) {
        float sc = sigma_t_leg[l16] + 1e-8f;
        float mv = mu_t_leg[l16];
        #pragma unroll
        for (int r = 0; r < 4; ++r) {
          int L = wv * 16 + quad * 4 + r;    // leg row = ib*32 + t
          ldiff[half * 32 + (L & 31)][(L >> 5) * 4 + l16] = oacc[r] * sc + mv;
        }
      }
    } // half

    // ================= pose MLP: 64 rows =================
    __syncthreads();   // ldiff ready, h2c free
    for (int i = tid; i < 64 * 32; i += 512) {
      int t = i >> 5, c = i & 31;
      float v = 0.f;
      if (c < 13) v = se[(size_t)(b0 + t) * 29 + c];
      else if (c < 29) { int ib, j; fmt_map(c - 13, ib, j); v = ldiff[t][ib * 4 + j]; }
      a0s[t * A0S + c] = (__bf16)v;
    }
    for (int i = tid; i < 64 * 16; i += 512) {   // legs output accumulation
      int t = i >> 4, k = i & 15;
      int ib, j; fmt_map(k, ib, j);
      legacc[t][k] += se[(size_t)(b0 + t) * 29 + 13 + k] + ldiff[t][ib * 4 + j];
    }
    __syncthreads();

    // ---- pose layer0: h1(64x512)
    {
      const __bf16* W0 = WP0p + (size_t)e * 16384;
      const float* b0v = bp0f + e * 512;
      bf16x8 bfr[4]; float bs[4];
      #pragma unroll
      for (int i = 0; i < 4; ++i) {
        int ct = wv * 4 + i;
        bfr[i] = *(const bf16x8*)(W0 + ((size_t)ct * 64 + lane) * 8);
        bs[i] = b0v[ct * 16 + l16];
      }
      for (int rt = 0; rt < 4; ++rt) {
        bf16x8 afr = *(const bf16x8*)&a0s[(rt * 16 + l16) * A0S + quad * 8];
        #pragma unroll
        for (int i = 0; i < 4; ++i) {
          f32x4 acc = {bs[i], bs[i], bs[i], bs[i]};
          acc = mfma16(afr, bfr[i], acc);
          int col = (wv * 4 + i) * 16 + l16;
          #pragma unroll
          for (int r = 0; r < 4; ++r)
            h1[(rt * 16 + quad * 4 + r) * H1S + col] = (__bf16)fmaxf(acc[r], 0.f);
        }
      }
    }
    __syncthreads();

    // ---- pose layer1 (64x512x512) + fused layer2 (N=13 -> 1 col-tile)
    {
      const __bf16* W1 = WP1p + (size_t)e * 262144;
      const __bf16* W2 = WP2p + (size_t)e * 8192;
      const float* b1v = bp1 + e * 512;
      float bvp = bp2[e * 26 + l16];
      f32x4 po = {bvp, bvp, bvp, bvp};       // waves 0..3 own row-tiles 0..3

      for (int cc2 = 0; cc2 < 2; ++cc2) {
        f32x4 acc[4][2];
        #pragma unroll
        for (int ct = 0; ct < 2; ++ct) {
          float bias = b1v[cc2 * 256 + wv * 32 + ct * 16 + l16];
          #pragma unroll
          for (int i = 0; i < 4; ++i) acc[i][ct] = (f32x4){bias, bias, bias, bias};
        }
        const __bf16* Wc = W1 + (size_t)(cc2 * 16 + wv * 2) * 8192;
        #pragma unroll 8
        for (int kt = 0; kt < 16; ++kt) {
          bf16x8 afr[4];
          #pragma unroll
          for (int i = 0; i < 4; ++i)
            afr[i] = *(const bf16x8*)&h1[(i * 16 + l16) * H1S + kt * 32 + quad * 8];
          #pragma unroll
          for (int ct = 0; ct < 2; ++ct) {
            bf16x8 bfr = *(const bf16x8*)(Wc + (((size_t)ct * 16 + kt) * 64 + lane) * 8);
            #pragma unroll
            for (int i = 0; i < 4; ++i) acc[i][ct] = mfma16(afr[i], bfr, acc[i][ct]);
          }
        }
        // stage in two 128-col halves (cols cg<4 then cg>=4)
        #pragma unroll
        for (int hh = 0; hh < 2; ++hh) {
          __syncthreads();
          if ((wv >> 2) == hh) {
            int cgl = wv & 3;
            #pragma unroll
            for (int i = 0; i < 4; ++i)
              #pragma unroll
              for (int ct = 0; ct < 2; ++ct)
                #pragma unroll
                for (int r = 0; r < 4; ++r)
                  h2c[(i * 16 + quad * 4 + r) * H2S + cgl * 32 + ct * 16 + l16] =
                      (__bf16)fmaxf(acc[i][ct][r], 0.f);
          }
          __syncthreads();
          if (wv < 4) {
            #pragma unroll
            for (int k2 = 0; k2 < 4; ++k2) {
              bf16x8 afr2 = *(const bf16x8*)&h2c[(wv * 16 + l16) * H2S + k2 * 32 + quad * 8];
              bf16x8 bfr2 = *(const bf16x8*)(W2 + ((size_t)(cc2 * 8 + hh * 4 + k2) * 64 + lane) * 8);
              po = mfma16(afr2, bfr2, po);
            }
          }
        }
      }
      // pose epilogue: accumulate into registers across ensembles
      if (wv < 4 && l16 < 13) {
        float sc = sigma_t_pose[l16] + 1e-8f;
        float mv = mu_t_pose[l16];
        #pragma unroll
        for (int r = 0; r < 4; ++r) {
          int row = wv * 16 + quad * 4 + r;
          posacc[r] += po[r] * sc + mv + se[(size_t)(b0 + row) * 29 + l16];
        }
      }
    }
  } // e

  // ================= final writes: mean over ensembles =================
  if (wv < 4 && l16 < 13) {
    #pragma unroll
    for (int r = 0; r < 4; ++r) {
      int row = wv * 16 + quad * 4 + r;
      out[(size_t)(b0 + row) * 29 + l16] = 0.25f * posacc[r];
    }
  }
  for (int i = tid; i < 64 * 16; i += 512) {
    int t = i >> 4, k = i & 15;
    out[(size_t)(b0 + t) * 29 + 13 + k] = 0.25f * legacc[t][k];
  }
}

// ---------------- launch ----------------------------------------------------
extern "C" void kernel_launch(void* const* d_in, const int* in_sizes, int n_in,
                              void* d_out, int out_size, void* d_ws, size_t ws_size,
                              hipStream_t stream) {
  const float* state = (const float*)d_in[0];
  const float* act = (const float*)d_in[1];
  const float* wl0 = (const float*)d_in[2];
  const float* bl0 = (const float*)d_in[3];
  const float* wl1 = (const float*)d_in[4];
  const float* bl1 = (const float*)d_in[5];
  const float* wl2 = (const float*)d_in[6];
  const float* bl2 = (const float*)d_in[7];
  const float* wp0 = (const float*)d_in[8];
  const float* bp0 = (const float*)d_in[9];
  const float* wp1 = (const float*)d_in[10];
  const float* bp1 = (const float*)d_in[11];
  const float* wp2 = (const float*)d_in[12];
  const float* bp2 = (const float*)d_in[13];
  const float* mu_leg = (const float*)d_in[14];
  const float* sigma_leg = (const float*)d_in[15];
  const float* mu_pose = (const float*)d_in[16];
  const float* sigma_pose = (const float*)d_in[17];
  const float* mu_t_leg = (const float*)d_in[18];
  const float* sigma_t_leg = (const float*)d_in[19];
  const float* mu_t_pose = (const float*)d_in[20];
  const float* sigma_t_pose = (const float*)d_in[21];
  float* out = (float*)d_out;

  char* ws = (char*)d_ws;
  __bf16* WL0p = (__bf16*)(ws);
  __bf16* WL1p = (__bf16*)(ws + 131072);
  __bf16* WL2p = (__bf16*)(ws + 2228224);
  __bf16* WP0p = (__bf16*)(ws + 2293760);
  __bf16* WP1p = (__bf16*)(ws + 2424832);
  __bf16* WP2p = (__bf16*)(ws + 4521984);
  float* bl0f = (float*)(ws + 4587520);
  float* bp0f = (float*)(ws + 4595712);

  prep_small<<<256, 256, 0, stream>>>(wl0, wl2, wp0, wp2, bl0, bp0,
                                      mu_leg, sigma_leg, mu_pose, sigma_pose,
                                      WL0p, WL2p, WP0p, WP2p, bl0f, bp0f);
  prep_w1<<<256, 256, 0, stream>>>(wl1, wp1, WL1p, WP1p);
  fused_kernel<<<256, 512, 0, stream>>>(state, act, bl1, bl2, bp1, bp2,
                                        mu_t_leg, sigma_t_leg, mu_t_pose, sigma_t_pose,
                                        WL0p, WL1p, WL2p, WP0p, WP1p, WP2p,
                                        bl0f, bp0f, out);
}

// Round 12
// 375.830 us; speedup vs baseline: 1.2927x; 1.0050x over previous
//
#include <hip/hip_runtime.h>

// NPG model: E=4 ensembles, B=16384, STATE=29, ACT=8, HID=512.
// R14 = R9 (368us banked) with ONE structural change: pose merged across
// ensemble PAIRS. Per pair p: legs(2p)->ldiffA, legs(2p+1)->ldiffB (leg code
// verbatim, parameterized ldiff target), then ONE 128-row pose pass shaped
// exactly like the proven leg MLP (8 waves rg x cg, acc[4][2], unroll 4,
// same h2c staging + fused L2; weights selected per row-half e=2p+rg).
// Gains: pose passes 4->2, pose L0 full-width, no wv<4 idle in pose L2.
// posacc ends split across rg groups -> 4KB LDS exchange at the end.
// LDS 162816 B (fits 160KiB; alloc is exact-sum per R9's 158720).
// Canary: WRITE_SIZE must stay 1856 KB (spill -> revert to R9).
// Prep: R9's split prep (proven 5x).

#define E_ 4
#define B_ 16384
#define H1S 520   // h1 row stride (bf16 elems), 16B-aligned, 2-way-bank-free
#define H2S 136   // h2 staging row stride
#define A0S 40    // a0 row stride

typedef float f32x4 __attribute__((ext_vector_type(4)));
typedef __bf16 bf16x8 __attribute__((ext_vector_type(8)));

__device__ __forceinline__ f32x4 mfma16(bf16x8 a, bf16x8 b, f32x4 c) {
  return __builtin_amdgcn_mfma_f32_16x16x32_bf16(a, b, c, 0, 0, 0);
}

// leg-format position mapping: output slot 13+k <- leg-block ib, component j
__device__ __forceinline__ void fmt_map(int k, int& ib, int& j) {
  if (k < 8) { ib = k >> 1; j = (k & 1) ? 2 : 0; }
  else { int k8 = k - 8; ib = k8 >> 1; j = (k8 & 1) ? 3 : 1; }
}

// ---------------- prep: pack weights into bf16 MFMA-B-fragment order --------
// Packed W (K x N): tiles (nt,kt) of 32x16; element ((nt*KT+kt)*64+lane)*8+j
// holds W[kt*32 + (lane>>4)*8 + j][nt*16 + (lane&15)]
__device__ __forceinline__ void pack_one(int idx, int per_e, int KT, int Kreal,
                                         int Nsrc, int Nval,
                                         const float* __restrict__ src,
                                         const float* __restrict__ sigma,
                                         __bf16* __restrict__ dst)
{
  int e = idx / per_e;
  int rem = idx - e * per_e;
  int g = rem >> 9;            // nt*KT + kt
  int nt = g / KT;
  int kt = g - nt * KT;
  int li = rem & 511;
  int lane = li >> 3, j = li & 7;
  int k = kt * 32 + (lane >> 4) * 8 + j;
  int n = nt * 16 + (lane & 15);
  float v = 0.f;
  if (k < Kreal && n < Nval) {
    v = src[(size_t)e * Kreal * Nsrc + (size_t)k * Nsrc + n];
    if (sigma) v *= 1.f / (sigma[k] + 1e-8f);   // fold input normalization
  }
  dst[idx] = (__bf16)v;
}

// Small matrices (W0 x2, W2 x2) + bias folds: gather path (cheap, cached).
__global__ void prep_small(const float* __restrict__ wl0, const float* __restrict__ wl2,
                           const float* __restrict__ wp0, const float* __restrict__ wp2,
                           const float* __restrict__ bl0, const float* __restrict__ bp0,
                           const float* __restrict__ mu_leg, const float* __restrict__ sigma_leg,
                           const float* __restrict__ mu_pose, const float* __restrict__ sigma_pose,
                           __bf16* __restrict__ WL0p, __bf16* __restrict__ WL2p,
                           __bf16* __restrict__ WP0p, __bf16* __restrict__ WP2p,
                           float* __restrict__ bl0f, float* __restrict__ bp0f)
{
  const int S0 = 65536, S2 = 32768;
  const int total = 2 * (S0 + S2) + 4096;
  for (int idx0 = blockIdx.x * blockDim.x + threadIdx.x; idx0 < total;
       idx0 += gridDim.x * blockDim.x) {
    int x = idx0;
    if (x < S0)              { pack_one(x, 16384, 1, 6, 512, 512, wl0, sigma_leg, WL0p); }
    else if ((x -= S0) < S2) { pack_one(x, 8192, 16, 512, 8, 8, wl2, nullptr, WL2p); }
    else if ((x -= S2) < S0) { pack_one(x, 16384, 1, 29, 512, 512, wp0, sigma_pose, WP0p); }
    else if ((x -= S0) < S2) { pack_one(x, 8192, 16, 512, 26, 16, wp2, nullptr, WP2p); }
    else {
      x -= S2;  // bias folds: b0' = b0 - sum_k mu[k]/(sigma[k]+eps) * W0[k,:]
      if (x < 2048) {
        int e = x >> 9, n = x & 511;
        float s = bl0[e * 512 + n];
        #pragma unroll
        for (int k = 0; k < 6; ++k)
          s -= mu_leg[k] / (sigma_leg[k] + 1e-8f) * wl0[(e * 6 + k) * 512 + n];
        bl0f[e * 512 + n] = s;
      } else {
        x -= 2048;
        int e = x >> 9, n = x & 511;
        float s = bp0[e * 512 + n];
        for (int k = 0; k < 29; ++k)
          s -= mu_pose[k] / (sigma_pose[k] + 1e-8f) * wp0[(e * 29 + k) * 512 + n];
        bp0f[e * 512 + n] = s;
      }
    }
  }
}

// W1 matrices (512x512): coalesced strip packer. Block = one (mat,e,nt)
// 512x16 column strip; stage f32->bf16 in LDS coalesced, emit contiguous.
__global__ __launch_bounds__(256) void prep_w1(const float* __restrict__ wl1,
                                               const float* __restrict__ wp1,
                                               __bf16* __restrict__ WL1p,
                                               __bf16* __restrict__ WP1p)
{
  __shared__ __bf16 st[512][20];
  const int b = blockIdx.x;          // 0..255: [mat(1) | e(2) | nt(5)]
  const float* src = (b & 128) ? wp1 : wl1;
  __bf16* dst = (b & 128) ? WP1p : WL1p;
  const int e = (b >> 5) & 3, nt = b & 31;
  src += (size_t)e * 262144 + nt * 16;
  dst += (size_t)e * 262144 + (size_t)nt * 8192;
  const int t = threadIdx.x;

  const int k0 = t >> 2, nq = t & 3;
  #pragma unroll
  for (int it = 0; it < 8; ++it) {
    int k = it * 64 + k0;
    f32x4 v = *(const f32x4*)(src + (size_t)k * 512 + nq * 4);
    #pragma unroll
    for (int j = 0; j < 4; ++j) st[k][nq * 4 + j] = (__bf16)v[j];
  }
  __syncthreads();
  #pragma unroll
  for (int it = 0; it < 4; ++it) {
    int lo = it * 256 + t;           // bf16x8 index 0..1023
    int kt = lo >> 6, lane = lo & 63;
    int kb = kt * 32 + (lane >> 4) * 8;
    int n = lane & 15;
    bf16x8 o;
    #pragma unroll
    for (int j = 0; j < 8; ++j) o[j] = st[kb + j][n];
    *(bf16x8*)(dst + (size_t)lo * 8) = o;
  }
}

// ---------------- fused model kernel ----------------------------------------
__global__ __launch_bounds__(512) void fused_kernel(
    const float* __restrict__ state, const float* __restrict__ act,
    const float* __restrict__ bl1, const float* __restrict__ bl2,
    const float* __restrict__ bp1, const float* __restrict__ bp2,
    const float* __restrict__ mu_t_leg, const float* __restrict__ sigma_t_leg,
    const float* __restrict__ mu_t_pose, const float* __restrict__ sigma_t_pose,
    const __bf16* __restrict__ WL0p, const __bf16* __restrict__ WL1p,
    const __bf16* __restrict__ WL2p, const __bf16* __restrict__ WP0p,
    const __bf16* __restrict__ WP1p, const __bf16* __restrict__ WP2p,
    const float* __restrict__ bl0f, const float* __restrict__ bp0f,
    float* __restrict__ out)
{
  __shared__ alignas(16) __bf16 h1[128 * H1S];   // 133120 B
  __shared__ alignas(16) __bf16 h2c[64 * H2S];   // 17408 B (union with a0)
  __shared__ float ldiffA[64][16];               // 4096 B (e even)
  __shared__ float ldiffB[64][16];               // 4096 B (e odd)
  __shared__ float legacc[64][16];               // 4096 B  -> total 162816 B
  __bf16* a0s = h2c;                             // a0 <=128*40 elems, fits

  const int tid = threadIdx.x;
  const int wv = tid >> 6;        // wave 0..7
  const int lane = tid & 63;
  const int quad = lane >> 4;
  const int l16 = lane & 15;
  const int b0 = blockIdx.x * 64;
  const int rg = wv >> 2, cg = wv & 3;

  for (int i = tid; i < 64 * 16; i += 512) ((float*)legacc)[i] = 0.f;
  f32x4 posacc = {0.f, 0.f, 0.f, 0.f};
  __syncthreads();

  for (int p = 0; p < 2; ++p) {
    const float* se0 = state + (size_t)(2 * p) * B_ * 29;
    const float* se1 = state + (size_t)(2 * p + 1) * B_ * 29;

    // ================= legs for e=2p and e=2p+1 =================
    for (int eh = 0; eh < 2; ++eh) {
      const int e = 2 * p + eh;
      const float* se = eh ? se1 : se0;
      const float* ae = act + (size_t)e * B_ * 8;
      float (*ldif)[16] = eh ? ldiffB : ldiffA;

      for (int half = 0; half < 2; ++half) {
        __syncthreads();   // h2c/a0 region free (prior readers done)
        // ---- a0 build: 128 rows (ib*32+t) x 32 cols (6 real)
        for (int i = tid; i < 128 * 32; i += 512) {
          int r = i >> 5, c = i & 31;
          float v = 0.f;
          if (c < 6) {
            int ib = r >> 5;
            int b = b0 + half * 32 + (r & 31);
            const float* sp = se + (size_t)b * 29;
            if (c == 0) v = sp[13 + 2 * ib];
            else if (c == 1) v = sp[21 + 2 * ib];
            else if (c == 2) v = sp[14 + 2 * ib];
            else if (c == 3) v = sp[22 + 2 * ib];
            else if (c == 4) v = ae[(size_t)b * 8 + 2 * ib];
            else v = ae[(size_t)b * 8 + 2 * ib + 1];
          }
          a0s[r * A0S + c] = (__bf16)v;
        }
        __syncthreads();

        // ---- layer0: h1(128x512) = relu(A0 @ W0 + b0')
        {
          const __bf16* W0 = WL0p + (size_t)e * 16384;
          const float* b0v = bl0f + e * 512;
          bf16x8 bfr[4]; float bs[4];
          #pragma unroll
          for (int i = 0; i < 4; ++i) {
            int ct = wv * 4 + i;
            bfr[i] = *(const bf16x8*)(W0 + ((size_t)ct * 64 + lane) * 8);
            bs[i] = b0v[ct * 16 + l16];
          }
          for (int rt = 0; rt < 8; ++rt) {
            bf16x8 afr = *(const bf16x8*)&a0s[(rt * 16 + l16) * A0S + quad * 8];
            #pragma unroll
            for (int i = 0; i < 4; ++i) {
              f32x4 acc = {bs[i], bs[i], bs[i], bs[i]};
              acc = mfma16(afr, bfr[i], acc);
              int col = (wv * 4 + i) * 16 + l16;
              #pragma unroll
              for (int r = 0; r < 4; ++r)
                h1[(rt * 16 + quad * 4 + r) * H1S + col] = (__bf16)fmaxf(acc[r], 0.f);
            }
          }
        }
        __syncthreads();

        // ---- layer1 (128x512x512) + fused layer2; wave tile 64r x 32c
        const __bf16* W1 = WL1p + (size_t)e * 262144;
        const __bf16* W2 = WL2p + (size_t)e * 8192;
        const float* b1v = bl1 + e * 512;
        float bv2 = (l16 < 8) ? bl2[e * 8 + l16] : 0.f;
        f32x4 oacc = {bv2, bv2, bv2, bv2};     // wave wv owns row-tile wv (l2)

        for (int cc = 0; cc < 4; ++cc) {
          f32x4 acc[4][2];
          #pragma unroll
          for (int ct = 0; ct < 2; ++ct) {
            float bias = b1v[cc * 128 + cg * 32 + ct * 16 + l16];
            #pragma unroll
            for (int i = 0; i < 4; ++i) acc[i][ct] = (f32x4){bias, bias, bias, bias};
          }
          const __bf16* Wc = W1 + (size_t)(cc * 8 + cg * 2) * 8192;
          #pragma unroll 4
          for (int kt = 0; kt < 16; ++kt) {
            bf16x8 afr[4];
            #pragma unroll
            for (int i = 0; i < 4; ++i)
              afr[i] = *(const bf16x8*)&h1[(rg * 64 + i * 16 + l16) * H1S + kt * 32 + quad * 8];
            #pragma unroll
            for (int ct = 0; ct < 2; ++ct) {
              bf16x8 bfr = *(const bf16x8*)(Wc + (((size_t)ct * 16 + kt) * 64 + lane) * 8);
              #pragma unroll
              for (int i = 0; i < 4; ++i) acc[i][ct] = mfma16(afr[i], bfr, acc[i][ct]);
            }
          }
          // stage h2 in two 64-row halves; owners accumulate layer2
          #pragma unroll
          for (int hh = 0; hh < 2; ++hh) {
            __syncthreads();
            if (rg == hh) {
              #pragma unroll
              for (int i = 0; i < 4; ++i)
                #pragma unroll
                for (int ct = 0; ct < 2; ++ct)
                  #pragma unroll
                  for (int r = 0; r < 4; ++r)
                    h2c[(i * 16 + quad * 4 + r) * H2S + cg * 32 + ct * 16 + l16] =
                        (__bf16)fmaxf(acc[i][ct][r], 0.f);
            }
            __syncthreads();
            if ((wv >> 2) == hh) {
              #pragma unroll
              for (int k2 = 0; k2 < 4; ++k2) {
                bf16x8 afr2 = *(const bf16x8*)&h2c[((wv & 3) * 16 + l16) * H2S + k2 * 32 + quad * 8];
                bf16x8 bfr2 = *(const bf16x8*)(W2 + ((size_t)(cc * 4 + k2) * 64 + lane) * 8);
                oacc = mfma16(afr2, bfr2, oacc);
              }
            }
          }
        }
        // ---- leg epilogue: ldif (only first 4 outputs used)
        if (l16 < 4) {
          float sc = sigma_t_leg[l16] + 1e-8f;
          float mv = mu_t_leg[l16];
          #pragma unroll
          for (int r = 0; r < 4; ++r) {
            int L = wv * 16 + quad * 4 + r;    // leg row = ib*32 + t
            ldif[half * 32 + (L & 31)][(L >> 5) * 4 + l16] = oacc[r] * sc + mv;
          }
        }
      } // half
    } // eh

    // ================= pose for the pair: 128 rows =================
    __syncthreads();   // ldiffA/B ready, h2c free
    for (int i = tid; i < 128 * 32; i += 512) {
      int r = i >> 5, c = i & 31;
      int eh = r >> 6, t = r & 63;
      const float* se = eh ? se1 : se0;
      float (*ldif)[16] = eh ? ldiffB : ldiffA;
      float v = 0.f;
      if (c < 13) v = se[(size_t)(b0 + t) * 29 + c];
      else if (c < 29) { int ib, j; fmt_map(c - 13, ib, j); v = ldif[t][ib * 4 + j]; }
      a0s[r * A0S + c] = (__bf16)v;
    }
    for (int i = tid; i < 2 * 64 * 16; i += 512) {   // legs output accumulation
      int eh = i >> 10, i2 = i & 1023;
      int t = i2 >> 4, k = i2 & 15;
      const float* se = eh ? se1 : se0;
      float (*ldif)[16] = eh ? ldiffB : ldiffA;
      int ib, j; fmt_map(k, ib, j);
      legacc[t][k] += se[(size_t)(b0 + t) * 29 + 13 + k] + ldif[t][ib * 4 + j];
    }
    __syncthreads();

    // ---- pose layer0: h1(128x512), per-row-half weights
    for (int eh = 0; eh < 2; ++eh) {
      const int e = 2 * p + eh;
      const __bf16* W0 = WP0p + (size_t)e * 16384;
      const float* b0v = bp0f + e * 512;
      bf16x8 bfr[4]; float bs[4];
      #pragma unroll
      for (int i = 0; i < 4; ++i) {
        int ct = wv * 4 + i;
        bfr[i] = *(const bf16x8*)(W0 + ((size_t)ct * 64 + lane) * 8);
        bs[i] = b0v[ct * 16 + l16];
      }
      for (int rt = eh * 4; rt < eh * 4 + 4; ++rt) {
        bf16x8 afr = *(const bf16x8*)&a0s[(rt * 16 + l16) * A0S + quad * 8];
        #pragma unroll
        for (int i = 0; i < 4; ++i) {
          f32x4 acc = {bs[i], bs[i], bs[i], bs[i]};
          acc = mfma16(afr, bfr[i], acc);
          int col = (wv * 4 + i) * 16 + l16;
          #pragma unroll
          for (int r = 0; r < 4; ++r)
            h1[(rt * 16 + quad * 4 + r) * H1S + col] = (__bf16)fmaxf(acc[r], 0.f);
        }
      }
    }
    __syncthreads();

    // ---- pose layer1 (128x512x512) + fused layer2 (leg-shaped)
    {
      const int epw = 2 * p + rg;              // e for this wave's rows
      const __bf16* W1 = WP1p + (size_t)epw * 262144;
      const __bf16* W2 = WP2p + (size_t)epw * 8192;
      const float* b1v = bp1 + epw * 512;
      float bvp = bp2[epw * 26 + l16];
      f32x4 po = {bvp, bvp, bvp, bvp};         // wave wv owns row-tile wv

      for (int cc = 0; cc < 4; ++cc) {
        f32x4 acc[4][2];
        #pragma unroll
        for (int ct = 0; ct < 2; ++ct) {
          float bias = b1v[cc * 128 + cg * 32 + ct * 16 + l16];
          #pragma unroll
          for (int i = 0; i < 4; ++i) acc[i][ct] = (f32x4){bias, bias, bias, bias};
        }
        const __bf16* Wc = W1 + (size_t)(cc * 8 + cg * 2) * 8192;
        #pragma unroll 4
        for (int kt = 0; kt < 16; ++kt) {
          bf16x8 afr[4];
          #pragma unroll
          for (int i = 0; i < 4; ++i)
            afr[i] = *(const bf16x8*)&h1[(rg * 64 + i * 16 + l16) * H1S + kt * 32 + quad * 8];
          #pragma unroll
          for (int ct = 0; ct < 2; ++ct) {
            bf16x8 bfr = *(const bf16x8*)(Wc + (((size_t)ct * 16 + kt) * 64 + lane) * 8);
            #pragma unroll
            for (int i = 0; i < 4; ++i) acc[i][ct] = mfma16(afr[i], bfr, acc[i][ct]);
          }
        }
        #pragma unroll
        for (int hh = 0; hh < 2; ++hh) {
          __syncthreads();
          if (rg == hh) {
            #pragma unroll
            for (int i = 0; i < 4; ++i)
              #pragma unroll
              for (int ct = 0; ct < 2; ++ct)
                #pragma unroll
                for (int r = 0; r < 4; ++r)
                  h2c[(i * 16 + quad * 4 + r) * H2S + cg * 32 + ct * 16 + l16] =
                      (__bf16)fmaxf(acc[i][ct][r], 0.f);
          }
          __syncthreads();
          if ((wv >> 2) == hh) {
            #pragma unroll
            for (int k2 = 0; k2 < 4; ++k2) {
              bf16x8 afr2 = *(const bf16x8*)&h2c[((wv & 3) * 16 + l16) * H2S + k2 * 32 + quad * 8];
              bf16x8 bfr2 = *(const bf16x8*)(W2 + ((size_t)(cc * 4 + k2) * 64 + lane) * 8);
              po = mfma16(afr2, bfr2, po);
            }
          }
        }
      }
      // pose epilogue: accumulate per wave (rows of e = 2p+rg)
      if (l16 < 13) {
        const float* se = rg ? se1 : se0;
        float sc = sigma_t_pose[l16] + 1e-8f;
        float mv = mu_t_pose[l16];
        #pragma unroll
        for (int r = 0; r < 4; ++r) {
          int row = (wv & 3) * 16 + quad * 4 + r;
          posacc[r] += po[r] * sc + mv + se[(size_t)(b0 + row) * 29 + l16];
        }
      }
    }
  } // p

  // ================= final: sum posacc across rg groups, write out =========
  __syncthreads();
  if (wv >= 4 && l16 < 13) {
    #pragma unroll
    for (int r = 0; r < 4; ++r)
      ldiffA[(wv & 3) * 16 + quad * 4 + r][l16] = posacc[r];
  }
  __syncthreads();
  if (wv < 4 && l16 < 13) {
    #pragma unroll
    for (int r = 0; r < 4; ++r) {
      int row = wv * 16 + quad * 4 + r;
      out[(size_t)(b0 + row) * 29 + l16] = 0.25f * (posacc[r] + ldiffA[row][l16]);
    }
  }
  for (int i = tid; i < 64 * 16; i += 512) {
    int t = i >> 4, k = i & 15;
    out[(size_t)(b0 + t) * 29 + 13 + k] = 0.25f * legacc[t][k];
  }
}

// ---------------- launch ----------------------------------------------------
extern "C" void kernel_launch(void* const* d_in, const int* in_sizes, int n_in,
                              void* d_out, int out_size, void* d_ws, size_t ws_size,
                              hipStream_t stream) {
  const float* state = (const float*)d_in[0];
  const float* act = (const float*)d_in[1];
  const float* wl0 = (const float*)d_in[2];
  const float* bl0 = (const float*)d_in[3];
  const float* wl1 = (const float*)d_in[4];
  const float* bl1 = (const float*)d_in[5];
  const float* wl2 = (const float*)d_in[6];
  const float* bl2 = (const float*)d_in[7];
  const float* wp0 = (const float*)d_in[8];
  const float* bp0 = (const float*)d_in[9];
  const float* wp1 = (const float*)d_in[10];
  const float* bp1 = (const float*)d_in[11];
  const float* wp2 = (const float*)d_in[12];
  const float* bp2 = (const float*)d_in[13];
  const float* mu_leg = (const float*)d_in[14];
  const float* sigma_leg = (const float*)d_in[15];
  const float* mu_pose = (const float*)d_in[16];
  const float* sigma_pose = (const float*)d_in[17];
  const float* mu_t_leg = (const float*)d_in[18];
  const float* sigma_t_leg = (const float*)d_in[19];
  const float* mu_t_pose = (const float*)d_in[20];
  const float* sigma_t_pose = (const float*)d_in[21];
  float* out = (float*)d_out;

  char* ws = (char*)d_ws;
  __bf16* WL0p = (__bf16*)(ws);
  __bf16* WL1p = (__bf16*)(ws + 131072);
  __bf16* WL2p = (__bf16*)(ws + 2228224);
  __bf16* WP0p = (__bf16*)(ws + 2293760);
  __bf16* WP1p = (__bf16*)(ws + 2424832);
  __bf16* WP2p = (__bf16*)(ws + 4521984);
  float* bl0f = (float*)(ws + 4587520);
  float* bp0f = (float*)(ws + 4595712);

  prep_small<<<256, 256, 0, stream>>>(wl0, wl2, wp0, wp2, bl0, bp0,
                                      mu_leg, sigma_leg, mu_pose, sigma_pose,
                                      WL0p, WL2p, WP0p, WP2p, bl0f, bp0f);
  prep_w1<<<256, 256, 0, stream>>>(wl1, wp1, WL1p, WP1p);
  fused_kernel<<<256, 512, 0, stream>>>(state, act, bl1, bl2, bp1, bp2,
                                        mu_t_leg, sigma_t_leg, mu_t_pose, sigma_t_pose,
                                        WL0p, WL1p, WL2p, WP0p, WP1p, WP2p,
                                        bl0f, bp0f, out);
}

// Round 13
// 362.296 us; speedup vs baseline: 1.3409x; 1.0374x over previous
//
#include <hip/hip_runtime.h>

// NPG model: E=4 ensembles, B=16384, STATE=29, ACT=8, HID=512.
// R15 = R9 VERBATIM — final banking of the session's measured best
// (368.0us total; fused 280us, profile-stable across 5 runs).
// Experiment ledger (all single-variable, all regressed or poisoned):
//   unroll {2,4,8} -> {301,280,299}; wide 64x64 tile -> 288-301 (conflicts
//   -45% but off critical path); LDS swizzles -> counters immune + spill;
//   2 blk/CU -> L2 weight-stream destroyed (FETCH 22x); operand-swap &
//   register-fused-L2 -> VGPR spill (WRITE_SIZE canary); pose-pair merge
//   -> 289; prep consolidation -> -20us. R9's exact configuration is a
//   sharp local optimum; remaining ~48% idle is barrier-drain structural
//   at HIP source level (guide m131-m141).
//  - fused_kernel: 256 blocks x 64 rows x 8 waves, 1 blk/CU, padded LDS
//    520/136, narrow 64x32 L1 wave tile, kt unroll 4, 96 VGPR.
//  - prep: split prep (prep_small gather + prep_w1 coalesced strip packer).

#define E_ 4
#define B_ 16384
#define H1S 520   // h1 row stride (bf16 elems), 16B-aligned, 2-way-bank-free
#define H2S 136   // h2 staging row stride
#define A0S 40    // a0 row stride

typedef float f32x4 __attribute__((ext_vector_type(4)));
typedef __bf16 bf16x8 __attribute__((ext_vector_type(8)));

__device__ __forceinline__ f32x4 mfma16(bf16x8 a, bf16x8 b, f32x4 c) {
  return __builtin_amdgcn_mfma_f32_16x16x32_bf16(a, b, c, 0, 0, 0);
}

// leg-format position mapping: output slot 13+k <- leg-block ib, component j
__device__ __forceinline__ void fmt_map(int k, int& ib, int& j) {
  if (k < 8) { ib = k >> 1; j = (k & 1) ? 2 : 0; }
  else { int k8 = k - 8; ib = k8 >> 1; j = (k8 & 1) ? 3 : 1; }
}

// ---------------- prep: pack weights into bf16 MFMA-B-fragment order --------
// Packed W (K x N): tiles (nt,kt) of 32x16; element ((nt*KT+kt)*64+lane)*8+j
// holds W[kt*32 + (lane>>4)*8 + j][nt*16 + (lane&15)]
__device__ __forceinline__ void pack_one(int idx, int per_e, int KT, int Kreal,
                                         int Nsrc, int Nval,
                                         const float* __restrict__ src,
                                         const float* __restrict__ sigma,
                                         __bf16* __restrict__ dst)
{
  int e = idx / per_e;
  int rem = idx - e * per_e;
  int g = rem >> 9;            // nt*KT + kt
  int nt = g / KT;
  int kt = g - nt * KT;
  int li = rem & 511;
  int lane = li >> 3, j = li & 7;
  int k = kt * 32 + (lane >> 4) * 8 + j;
  int n = nt * 16 + (lane & 15);
  float v = 0.f;
  if (k < Kreal && n < Nval) {
    v = src[(size_t)e * Kreal * Nsrc + (size_t)k * Nsrc + n];
    if (sigma) v *= 1.f / (sigma[k] + 1e-8f);   // fold input normalization
  }
  dst[idx] = (__bf16)v;
}

// Small matrices (W0 x2, W2 x2) + bias folds: gather path (cheap, cached).
__global__ void prep_small(const float* __restrict__ wl0, const float* __restrict__ wl2,
                           const float* __restrict__ wp0, const float* __restrict__ wp2,
                           const float* __restrict__ bl0, const float* __restrict__ bp0,
                           const float* __restrict__ mu_leg, const float* __restrict__ sigma_leg,
                           const float* __restrict__ mu_pose, const float* __restrict__ sigma_pose,
                           __bf16* __restrict__ WL0p, __bf16* __restrict__ WL2p,
                           __bf16* __restrict__ WP0p, __bf16* __restrict__ WP2p,
                           float* __restrict__ bl0f, float* __restrict__ bp0f)
{
  const int S0 = 65536, S2 = 32768;
  const int total = 2 * (S0 + S2) + 4096;
  for (int idx0 = blockIdx.x * blockDim.x + threadIdx.x; idx0 < total;
       idx0 += gridDim.x * blockDim.x) {
    int x = idx0;
    if (x < S0)              { pack_one(x, 16384, 1, 6, 512, 512, wl0, sigma_leg, WL0p); }
    else if ((x -= S0) < S2) { pack_one(x, 8192, 16, 512, 8, 8, wl2, nullptr, WL2p); }
    else if ((x -= S2) < S0) { pack_one(x, 16384, 1, 29, 512, 512, wp0, sigma_pose, WP0p); }
    else if ((x -= S0) < S2) { pack_one(x, 8192, 16, 512, 26, 16, wp2, nullptr, WP2p); }
    else {
      x -= S2;  // bias folds: b0' = b0 - sum_k mu[k]/(sigma[k]+eps) * W0[k,:]
      if (x < 2048) {
        int e = x >> 9, n = x & 511;
        float s = bl0[e * 512 + n];
        #pragma unroll
        for (int k = 0; k < 6; ++k)
          s -= mu_leg[k] / (sigma_leg[k] + 1e-8f) * wl0[(e * 6 + k) * 512 + n];
        bl0f[e * 512 + n] = s;
      } else {
        x -= 2048;
        int e = x >> 9, n = x & 511;
        float s = bp0[e * 512 + n];
        for (int k = 0; k < 29; ++k)
          s -= mu_pose[k] / (sigma_pose[k] + 1e-8f) * wp0[(e * 29 + k) * 512 + n];
        bp0f[e * 512 + n] = s;
      }
    }
  }
}

// W1 matrices (512x512): coalesced strip packer. Block = one (mat,e,nt)
// 512x16 column strip; stage f32->bf16 in LDS coalesced, emit contiguous.
__global__ __launch_bounds__(256) void prep_w1(const float* __restrict__ wl1,
                                               const float* __restrict__ wp1,
                                               __bf16* __restrict__ WL1p,
                                               __bf16* __restrict__ WP1p)
{
  __shared__ __bf16 st[512][20];
  const int b = blockIdx.x;          // 0..255: [mat(1) | e(2) | nt(5)]
  const float* src = (b & 128) ? wp1 : wl1;
  __bf16* dst = (b & 128) ? WP1p : WL1p;
  const int e = (b >> 5) & 3, nt = b & 31;
  src += (size_t)e * 262144 + nt * 16;
  dst += (size_t)e * 262144 + (size_t)nt * 8192;
  const int t = threadIdx.x;

  const int k0 = t >> 2, nq = t & 3;
  #pragma unroll
  for (int it = 0; it < 8; ++it) {
    int k = it * 64 + k0;
    f32x4 v = *(const f32x4*)(src + (size_t)k * 512 + nq * 4);
    #pragma unroll
    for (int j = 0; j < 4; ++j) st[k][nq * 4 + j] = (__bf16)v[j];
  }
  __syncthreads();
  #pragma unroll
  for (int it = 0; it < 4; ++it) {
    int lo = it * 256 + t;           // bf16x8 index 0..1023
    int kt = lo >> 6, lane = lo & 63;
    int kb = kt * 32 + (lane >> 4) * 8;
    int n = lane & 15;
    bf16x8 o;
    #pragma unroll
    for (int j = 0; j < 8; ++j) o[j] = st[kb + j][n];
    *(bf16x8*)(dst + (size_t)lo * 8) = o;
  }
}

// ---------------- fused model kernel (R0/R2/R9 verbatim) --------------------
__global__ __launch_bounds__(512) void fused_kernel(
    const float* __restrict__ state, const float* __restrict__ act,
    const float* __restrict__ bl1, const float* __restrict__ bl2,
    const float* __restrict__ bp1, const float* __restrict__ bp2,
    const float* __restrict__ mu_t_leg, const float* __restrict__ sigma_t_leg,
    const float* __restrict__ mu_t_pose, const float* __restrict__ sigma_t_pose,
    const __bf16* __restrict__ WL0p, const __bf16* __restrict__ WL1p,
    const __bf16* __restrict__ WL2p, const __bf16* __restrict__ WP0p,
    const __bf16* __restrict__ WP1p, const __bf16* __restrict__ WP2p,
    const float* __restrict__ bl0f, const float* __restrict__ bp0f,
    float* __restrict__ out)
{
  __shared__ alignas(16) __bf16 h1[128 * H1S];   // 133120 B
  __shared__ alignas(16) __bf16 h2c[64 * H2S];   // 17408 B (union with a0)
  __shared__ float ldiff[64][16];                // 4096 B
  __shared__ float legacc[64][16];               // 4096 B  -> total 158 KB
  __bf16* a0s = h2c;                             // a0 <=128*40=10240B, fits

  const int tid = threadIdx.x;
  const int wv = tid >> 6;        // wave 0..7
  const int lane = tid & 63;
  const int quad = lane >> 4;
  const int l16 = lane & 15;
  const int b0 = blockIdx.x * 64;

  for (int i = tid; i < 64 * 16; i += 512) ((float*)legacc)[i] = 0.f;
  f32x4 posacc = {0.f, 0.f, 0.f, 0.f};
  __syncthreads();

  for (int e = 0; e < E_; ++e) {
    const float* se = state + (size_t)e * B_ * 29;
    const float* ae = act + (size_t)e * B_ * 8;

    // ================= leg MLP: 2 passes of 128 leg rows =================
    for (int half = 0; half < 2; ++half) {
      __syncthreads();   // h2c/a0 region free (prior readers done)
      // ---- a0 build: 128 rows (ib*32+t) x 32 cols (6 real)
      for (int i = tid; i < 128 * 32; i += 512) {
        int r = i >> 5, c = i & 31;
        float v = 0.f;
        if (c < 6) {
          int ib = r >> 5;
          int b = b0 + half * 32 + (r & 31);
          const float* sp = se + (size_t)b * 29;
          if (c == 0) v = sp[13 + 2 * ib];
          else if (c == 1) v = sp[21 + 2 * ib];
          else if (c == 2) v = sp[14 + 2 * ib];
          else if (c == 3) v = sp[22 + 2 * ib];
          else if (c == 4) v = ae[(size_t)b * 8 + 2 * ib];
          else v = ae[(size_t)b * 8 + 2 * ib + 1];
        }
        a0s[r * A0S + c] = (__bf16)v;
      }
      __syncthreads();

      // ---- layer0: h1(128x512) = relu(A0 @ W0 + b0'); wave owns 4 col-tiles
      {
        const __bf16* W0 = WL0p + (size_t)e * 16384;
        const float* b0v = bl0f + e * 512;
        bf16x8 bfr[4]; float bs[4];
        #pragma unroll
        for (int i = 0; i < 4; ++i) {
          int ct = wv * 4 + i;
          bfr[i] = *(const bf16x8*)(W0 + ((size_t)ct * 64 + lane) * 8);
          bs[i] = b0v[ct * 16 + l16];
        }
        for (int rt = 0; rt < 8; ++rt) {
          bf16x8 afr = *(const bf16x8*)&a0s[(rt * 16 + l16) * A0S + quad * 8];
          #pragma unroll
          for (int i = 0; i < 4; ++i) {
            f32x4 acc = {bs[i], bs[i], bs[i], bs[i]};
            acc = mfma16(afr, bfr[i], acc);
            int col = (wv * 4 + i) * 16 + l16;
            #pragma unroll
            for (int r = 0; r < 4; ++r)
              h1[(rt * 16 + quad * 4 + r) * H1S + col] = (__bf16)fmaxf(acc[r], 0.f);
          }
        }
      }
      __syncthreads();

      // ---- layer1 (128x512x512) + fused layer2; wave tile 64r x 32c
      const __bf16* W1 = WL1p + (size_t)e * 262144;
      const __bf16* W2 = WL2p + (size_t)e * 8192;
      const float* b1v = bl1 + e * 512;
      const int rg = wv >> 2, cg = wv & 3;
      float bv2 = (l16 < 8) ? bl2[e * 8 + l16] : 0.f;
      f32x4 oacc = {bv2, bv2, bv2, bv2};     // wave wv owns row-tile wv (l2)

      for (int cc = 0; cc < 4; ++cc) {
        f32x4 acc[4][2];
        #pragma unroll
        for (int ct = 0; ct < 2; ++ct) {
          float bias = b1v[cc * 128 + cg * 32 + ct * 16 + l16];
          #pragma unroll
          for (int i = 0; i < 4; ++i) acc[i][ct] = (f32x4){bias, bias, bias, bias};
        }
        const __bf16* Wc = W1 + (size_t)(cc * 8 + cg * 2) * 8192;
        #pragma unroll 4
        for (int kt = 0; kt < 16; ++kt) {
          bf16x8 afr[4];
          #pragma unroll
          for (int i = 0; i < 4; ++i)
            afr[i] = *(const bf16x8*)&h1[(rg * 64 + i * 16 + l16) * H1S + kt * 32 + quad * 8];
          #pragma unroll
          for (int ct = 0; ct < 2; ++ct) {
            bf16x8 bfr = *(const bf16x8*)(Wc + (((size_t)ct * 16 + kt) * 64 + lane) * 8);
            #pragma unroll
            for (int i = 0; i < 4; ++i) acc[i][ct] = mfma16(afr[i], bfr, acc[i][ct]);
          }
        }
        // stage h2 in two 64-row halves; owners accumulate layer2
        #pragma unroll
        for (int hh = 0; hh < 2; ++hh) {
          __syncthreads();
          if (rg == hh) {
            #pragma unroll
            for (int i = 0; i < 4; ++i)
              #pragma unroll
              for (int ct = 0; ct < 2; ++ct)
                #pragma unroll
                for (int r = 0; r < 4; ++r)
                  h2c[(i * 16 + quad * 4 + r) * H2S + cg * 32 + ct * 16 + l16] =
                      (__bf16)fmaxf(acc[i][ct][r], 0.f);
          }
          __syncthreads();
          if ((wv >> 2) == hh) {
            #pragma unroll
            for (int k2 = 0; k2 < 4; ++k2) {
              bf16x8 afr2 = *(const bf16x8*)&h2c[((wv & 3) * 16 + l16) * H2S + k2 * 32 + quad * 8];
              bf16x8 bfr2 = *(const bf16x8*)(W2 + ((size_t)(cc * 4 + k2) * 64 + lane) * 8);
              oacc = mfma16(afr2, bfr2, oacc);
            }
          }
        }
      }
      // ---- leg epilogue: ldiff (only first 4 outputs used)
      if (l16 < 4) {
        float sc = sigma_t_leg[l16] + 1e-8f;
        float mv = mu_t_leg[l16];
        #pragma unroll
        for (int r = 0; r < 4; ++r) {
          int L = wv * 16 + quad * 4 + r;    // leg row = ib*32 + t
          ldiff[half * 32 + (L & 31)][(L >> 5) * 4 + l16] = oacc[r] * sc + mv;
        }
      }
    } // half

    // ================= pose MLP: 64 rows =================
    __syncthreads();   // ldiff ready, h2c free
    for (int i = tid; i < 64 * 32; i += 512) {
      int t = i >> 5, c = i & 31;
      float v = 0.f;
      if (c < 13) v = se[(size_t)(b0 + t) * 29 + c];
      else if (c < 29) { int ib, j; fmt_map(c - 13, ib, j); v = ldiff[t][ib * 4 + j]; }
      a0s[t * A0S + c] = (__bf16)v;
    }
    for (int i = tid; i < 64 * 16; i += 512) {   // legs output accumulation
      int t = i >> 4, k = i & 15;
      int ib, j; fmt_map(k, ib, j);
      legacc[t][k] += se[(size_t)(b0 + t) * 29 + 13 + k] + ldiff[t][ib * 4 + j];
    }
    __syncthreads();

    // ---- pose layer0: h1(64x512)
    {
      const __bf16* W0 = WP0p + (size_t)e * 16384;
      const float* b0v = bp0f + e * 512;
      bf16x8 bfr[4]; float bs[4];
      #pragma unroll
      for (int i = 0; i < 4; ++i) {
        int ct = wv * 4 + i;
        bfr[i] = *(const bf16x8*)(W0 + ((size_t)ct * 64 + lane) * 8);
        bs[i] = b0v[ct * 16 + l16];
      }
      for (int rt = 0; rt < 4; ++rt) {
        bf16x8 afr = *(const bf16x8*)&a0s[(rt * 16 + l16) * A0S + quad * 8];
        #pragma unroll
        for (int i = 0; i < 4; ++i) {
          f32x4 acc = {bs[i], bs[i], bs[i], bs[i]};
          acc = mfma16(afr, bfr[i], acc);
          int col = (wv * 4 + i) * 16 + l16;
          #pragma unroll
          for (int r = 0; r < 4; ++r)
            h1[(rt * 16 + quad * 4 + r) * H1S + col] = (__bf16)fmaxf(acc[r], 0.f);
        }
      }
    }
    __syncthreads();

    // ---- pose layer1 (64x512x512) + fused layer2 (N=13 -> 1 col-tile)
    {
      const __bf16* W1 = WP1p + (size_t)e * 262144;
      const __bf16* W2 = WP2p + (size_t)e * 8192;
      const float* b1v = bp1 + e * 512;
      float bvp = bp2[e * 26 + l16];
      f32x4 po = {bvp, bvp, bvp, bvp};       // waves 0..3 own row-tiles 0..3

      for (int cc2 = 0; cc2 < 2; ++cc2) {
        f32x4 acc[4][2];
        #pragma unroll
        for (int ct = 0; ct < 2; ++ct) {
          float bias = b1v[cc2 * 256 + wv * 32 + ct * 16 + l16];
          #pragma unroll
          for (int i = 0; i < 4; ++i) acc[i][ct] = (f32x4){bias, bias, bias, bias};
        }
        const __bf16* Wc = W1 + (size_t)(cc2 * 16 + wv * 2) * 8192;
        #pragma unroll 4
        for (int kt = 0; kt < 16; ++kt) {
          bf16x8 afr[4];
          #pragma unroll
          for (int i = 0; i < 4; ++i)
            afr[i] = *(const bf16x8*)&h1[(i * 16 + l16) * H1S + kt * 32 + quad * 8];
          #pragma unroll
          for (int ct = 0; ct < 2; ++ct) {
            bf16x8 bfr = *(const bf16x8*)(Wc + (((size_t)ct * 16 + kt) * 64 + lane) * 8);
            #pragma unroll
            for (int i = 0; i < 4; ++i) acc[i][ct] = mfma16(afr[i], bfr, acc[i][ct]);
          }
        }
        // stage in two 128-col halves (cols cg<4 then cg>=4)
        #pragma unroll
        for (int hh = 0; hh < 2; ++hh) {
          __syncthreads();
          if ((wv >> 2) == hh) {
            int cgl = wv & 3;
            #pragma unroll
            for (int i = 0; i < 4; ++i)
              #pragma unroll
              for (int ct = 0; ct < 2; ++ct)
                #pragma unroll
                for (int r = 0; r < 4; ++r)
                  h2c[(i * 16 + quad * 4 + r) * H2S + cgl * 32 + ct * 16 + l16] =
                      (__bf16)fmaxf(acc[i][ct][r], 0.f);
          }
          __syncthreads();
          if (wv < 4) {
            #pragma unroll
            for (int k2 = 0; k2 < 4; ++k2) {
              bf16x8 afr2 = *(const bf16x8*)&h2c[(wv * 16 + l16) * H2S + k2 * 32 + quad * 8];
              bf16x8 bfr2 = *(const bf16x8*)(W2 + ((size_t)(cc2 * 8 + hh * 4 + k2) * 64 + lane) * 8);
              po = mfma16(afr2, bfr2, po);
            }
          }
        }
      }
      // pose epilogue: accumulate into registers across ensembles
      if (wv < 4 && l16 < 13) {
        float sc = sigma_t_pose[l16] + 1e-8f;
        float mv = mu_t_pose[l16];
        #pragma unroll
        for (int r = 0; r < 4; ++r) {
          int row = wv * 16 + quad * 4 + r;
          posacc[r] += po[r] * sc + mv + se[(size_t)(b0 + row) * 29 + l16];
        }
      }
    }
  } // e

  // ================= final writes: mean over ensembles =================
  if (wv < 4 && l16 < 13) {
    #pragma unroll
    for (int r = 0; r < 4; ++r) {
      int row = wv * 16 + quad * 4 + r;
      out[(size_t)(b0 + row) * 29 + l16] = 0.25f * posacc[r];
    }
  }
  for (int i = tid; i < 64 * 16; i += 512) {
    int t = i >> 4, k = i & 15;
    out[(size_t)(b0 + t) * 29 + 13 + k] = 0.25f * legacc[t][k];
  }
}

// ---------------- launch ----------------------------------------------------
extern "C" void kernel_launch(void* const* d_in, const int* in_sizes, int n_in,
                              void* d_out, int out_size, void* d_ws, size_t ws_size,
                              hipStream_t stream) {
  const float* state = (const float*)d_in[0];
  const float* act = (const float*)d_in[1];
  const float* wl0 = (const float*)d_in[2];
  const float* bl0 = (const float*)d_in[3];
  const float* wl1 = (const float*)d_in[4];
  const float* bl1 = (const float*)d_in[5];
  const float* wl2 = (const float*)d_in[6];
  const float* bl2 = (const float*)d_in[7];
  const float* wp0 = (const float*)d_in[8];
  const float* bp0 = (const float*)d_in[9];
  const float* wp1 = (const float*)d_in[10];
  const float* bp1 = (const float*)d_in[11];
  const float* wp2 = (const float*)d_in[12];
  const float* bp2 = (const float*)d_in[13];
  const float* mu_leg = (const float*)d_in[14];
  const float* sigma_leg = (const float*)d_in[15];
  const float* mu_pose = (const float*)d_in[16];
  const float* sigma_pose = (const float*)d_in[17];
  const float* mu_t_leg = (const float*)d_in[18];
  const float* sigma_t_leg = (const float*)d_in[19];
  const float* mu_t_pose = (const float*)d_in[20];
  const float* sigma_t_pose = (const float*)d_in[21];
  float* out = (float*)d_out;

  char* ws = (char*)d_ws;
  __bf16* WL0p = (__bf16*)(ws);
  __bf16* WL1p = (__bf16*)(ws + 131072);
  __bf16* WL2p = (__bf16*)(ws + 2228224);
  __bf16* WP0p = (__bf16*)(ws + 2293760);
  __bf16* WP1p = (__bf16*)(ws + 2424832);
  __bf16* WP2p = (__bf16*)(ws + 4521984);
  float* bl0f = (float*)(ws + 4587520);
  float* bp0f = (float*)(ws + 4595712);

  prep_small<<<256, 256, 0, stream>>>(wl0, wl2, wp0, wp2, bl0, bp0,
                                      mu_leg, sigma_leg, mu_pose, sigma_pose,
                                      WL0p, WL2p, WP0p, WP2p, bl0f, bp0f);
  prep_w1<<<256, 256, 0, stream>>>(wl1, wp1, WL1p, WP1p);
  fused_kernel<<<256, 512, 0, stream>>>(state, act, bl1, bl2, bp1, bp2,
                                        mu_t_leg, sigma_t_leg, mu_t_pose, sigma_t_pose,
                                        WL0p, WL1p, WL2p, WP0p, WP1p, WP2p,
                                        bl0f, bp0f, out);
}